// Round 1
// baseline (1084.272 us; speedup 1.0000x reference)
//
#include <hip/hip_runtime.h>
#include <hip/hip_bf16.h>
#include <math.h>

#define HIDDEN 4096
#define NH 32
#define NKV 8
#define HD 128
#define QSZ 4096
#define KVSZ 1024
#define QKV_N 6144
#define Bb 2
#define Ss 2048
#define MTOT 4096   // B*S
#define SCALE 0.08838834764831845f

typedef __attribute__((ext_vector_type(8))) __bf16 bf16x8;
typedef __attribute__((ext_vector_type(4))) __bf16 bf16x4;
typedef __attribute__((ext_vector_type(4))) float f32x4;

__device__ __forceinline__ f32x4 mfma_bf16(bf16x8 a, bf16x8 b, f32x4 c) {
  return __builtin_amdgcn_mfma_f32_16x16x32_bf16(a, b, c, 0, 0, 0);
}

// global -> LDS direct copy, 16B per lane. LDS dest must be wave-uniform;
// lane l lands at dst + l*16.
__device__ __forceinline__ void gload_lds16(const void* g, void* l) {
  __builtin_amdgcn_global_load_lds((const __attribute__((address_space(1))) void*)g,
                                   (__attribute__((address_space(3))) void*)l, 16, 0, 0);
}

// ---------------- elementwise f32 -> bf16 (vectorized) ----------------
__global__ __launch_bounds__(256) void f2b(const float* __restrict__ in,
                                           __bf16* __restrict__ out, long n4) {
  for (long i = (long)blockIdx.x * blockDim.x + threadIdx.x; i < n4;
       i += (long)gridDim.x * blockDim.x) {
    float4 v = ((const float4*)in)[i];
    bf16x4 o = {(__bf16)v.x, (__bf16)v.y, (__bf16)v.z, (__bf16)v.w};
    ((bf16x4*)out)[i] = o;
  }
}

// ---------------- transpose + convert: w[K][N] f32 -> wT[N][K] bf16 ----------------
__global__ __launch_bounds__(256) void transpose_conv(const float* __restrict__ w,
                                                      __bf16* __restrict__ wT,
                                                      int K, int N) {
  __shared__ __bf16 tile[64][65];
  int nb = N >> 6;
  int kt = blockIdx.x / nb, nt = blockIdx.x % nb;
  for (int i = threadIdx.x; i < 64 * 64; i += 256) {
    int kl = i >> 6, nl = i & 63;
    tile[kl][nl] = (__bf16)w[(size_t)(kt * 64 + kl) * N + (nt * 64 + nl)];
  }
  __syncthreads();
  for (int i = threadIdx.x; i < 64 * 64; i += 256) {
    int nl = i >> 6, kl = i & 63;
    wT[(size_t)(nt * 64 + nl) * K + (kt * 64 + kl)] = tile[kl][nl];
  }
}

// ---------------- GEMM: C[M][N] = A[M][K] * Bt[N][K]^T (+bias) ----------------
// 128x128 tile, BK=32, 4 waves (2x2 quadrants of 64x64), 16x16x32 bf16 MFMA.
__global__ __launch_bounds__(256) void gemm_bt(const __bf16* __restrict__ A,
                                               const __bf16* __restrict__ Bt,
                                               const float* __restrict__ bias,
                                               void* __restrict__ Cout,
                                               int M, int N, int K, int out_bf16) {
  __shared__ __bf16 As[128 * 32];
  __shared__ __bf16 Bs[128 * 32];
  const int tid = threadIdx.x;
  const int wave = tid >> 6, lane = tid & 63;
  const int nbn = N >> 7;
  const int bm = blockIdx.x / nbn, bn = blockIdx.x % nbn;
  const int m0 = bm << 7, n0 = bn << 7;
  const int lr = lane & 15, hi = lane >> 4;
  const int srow = lane >> 2, scol = (lane & 3) << 3;

  const __bf16* gA = A + (size_t)(m0 + srow) * K + scol;
  const __bf16* gB = Bt + (size_t)(n0 + srow) * K + scol;
  __bf16* lA = As + wave * 1024;  // wave stages rows [32w, 32w+32)
  __bf16* lB = Bs + wave * 1024;

  const f32x4 fz = {0.f, 0.f, 0.f, 0.f};
  f32x4 acc[4][4];
#pragma unroll
  for (int i = 0; i < 4; i++)
#pragma unroll
    for (int j = 0; j < 4; j++) acc[i][j] = fz;

  const int mrow = (wave >> 1) * 64, ncol = (wave & 1) * 64;

  for (int k0 = 0; k0 < K; k0 += 32) {
    __syncthreads();
    gload_lds16(gA + (size_t)(wave * 32) * K + k0, lA);
    gload_lds16(gA + (size_t)(wave * 32 + 16) * K + k0, lA + 512);
    gload_lds16(gB + (size_t)(wave * 32) * K + k0, lB);
    gload_lds16(gB + (size_t)(wave * 32 + 16) * K + k0, lB + 512);
    __syncthreads();
    bf16x8 af[4], bfr[4];
#pragma unroll
    for (int i = 0; i < 4; i++)
      af[i] = *(const bf16x8*)(As + (mrow + i * 16 + lr) * 32 + hi * 8);
#pragma unroll
    for (int i = 0; i < 4; i++)
      bfr[i] = *(const bf16x8*)(Bs + (ncol + i * 16 + lr) * 32 + hi * 8);
#pragma unroll
    for (int i = 0; i < 4; i++)
#pragma unroll
      for (int j = 0; j < 4; j++) acc[i][j] = mfma_bf16(af[i], bfr[j], acc[i][j]);
  }

  // epilogue: D[row=(lane>>4)*4+r][col=lane&15] per 16x16 tile (verified m89 layout)
#pragma unroll
  for (int i = 0; i < 4; i++) {
    int row_base = m0 + mrow + i * 16 + hi * 4;
#pragma unroll
    for (int j = 0; j < 4; j++) {
      int col = n0 + ncol + j * 16 + lr;
      float bv = bias ? bias[col] : 0.f;
#pragma unroll
      for (int r = 0; r < 4; r++) {
        int row = row_base + r;
        float v = acc[i][j][r] + bv;
        if (out_bf16)
          ((__bf16*)Cout)[(size_t)row * N + col] = (__bf16)v;
        else
          ((float*)Cout)[(size_t)row * N + col] = v;
      }
    }
  }
}

// ---------------- RoPE for q and k ----------------
__global__ __launch_bounds__(256) void rope_qk(const __bf16* __restrict__ qkv,
                                               const int* __restrict__ pos,
                                               __bf16* __restrict__ Qo,
                                               __bf16* __restrict__ Ko) {
  int bs = blockIdx.x;
  int b = bs / Ss, s = bs % Ss;
  float p = (float)pos[s];
  const __bf16* src = qkv + (size_t)bs * QKV_N;
  for (int t = threadIdx.x; t < (NH + NKV) * 64; t += 256) {
    int head = t >> 6, i = t & 63;
    float inv = powf(10000.f, -(float)i * (1.f / 64.f));
    float sn, cs;
    sincosf(p * inv, &sn, &cs);
    if (head < NH) {
      float x1 = (float)src[head * HD + i];
      float x2 = (float)src[head * HD + i + 64];
      __bf16* dst = Qo + ((size_t)(b * NH + head) * Ss + s) * HD;
      dst[i] = (__bf16)(x1 * cs - x2 * sn);
      dst[i + 64] = (__bf16)(x2 * cs + x1 * sn);
    } else {
      int kh = head - NH;
      float x1 = (float)src[QSZ + kh * HD + i];
      float x2 = (float)src[QSZ + kh * HD + i + 64];
      __bf16* dst = Ko + ((size_t)(b * NKV + kh) * Ss + s) * HD;
      dst[i] = (__bf16)(x1 * cs - x2 * sn);
      dst[i + 64] = (__bf16)(x2 * cs + x1 * sn);
    }
  }
}

// ---------------- V transpose: qkv v-part -> Vt[B][KVH][D][S] ----------------
__global__ __launch_bounds__(256) void vtrans(const __bf16* __restrict__ qkv,
                                              __bf16* __restrict__ Vt) {
  __shared__ __bf16 tile[128][65];
  int bid = blockIdx.x;
  int st_ = bid & 31;
  int kvh = (bid >> 5) & 7;
  int b = bid >> 8;
  int s0 = st_ * 64;
  const __bf16* src = qkv + (size_t)(b * Ss) * QKV_N + (QSZ + KVSZ) + kvh * HD;
  for (int i = threadIdx.x; i < 64 * 128; i += 256) {
    int sl = i >> 7, d = i & 127;
    tile[d][sl] = src[(size_t)(s0 + sl) * QKV_N + d];
  }
  __syncthreads();
  __bf16* dst = Vt + (size_t)(b * NKV + kvh) * HD * Ss;
  for (int i = threadIdx.x; i < 64 * 128; i += 256) {
    int dl = i >> 6, sl = i & 63;
    dst[(size_t)dl * Ss + s0 + sl] = tile[dl][sl];
  }
}

// ---------------- causal flash attention ----------------
// grid: B*NH*(S/64); block 256 = 4 waves, each wave owns 16 q rows.
__global__ __launch_bounds__(256) void attn_fwd(const __bf16* __restrict__ Q,
                                                const __bf16* __restrict__ Kk,
                                                const __bf16* __restrict__ Vt,
                                                __bf16* __restrict__ Oa) {
  __shared__ __bf16 Kl[32 * 128];   // [32 keys][128 d]
  __shared__ __bf16 Vl[128 * 32];   // [128 d][32 keys]
  __shared__ __bf16 Pl[4][16 * 32]; // per-wave [16 q][32 keys]
  const int tid = threadIdx.x, wave = tid >> 6, lane = tid & 63;
  const int nqb = Ss / 64;
  const int bid = blockIdx.x;
  const int b = bid / (NH * nqb);
  const int h = (bid / nqb) % NH;
  const int qb = bid % nqb;
  const int q0 = qb * 64;
  const int kvh = h >> 2;
  const int lr = lane & 15, hi = lane >> 4;
  const int srow = lane >> 2, scol = (lane & 3) << 3;
  const f32x4 fz = {0.f, 0.f, 0.f, 0.f};

  const __bf16* qbase = Q + ((size_t)(b * NH + h) * Ss + q0 + wave * 16 + lr) * HD;
  bf16x8 qf[4];
#pragma unroll
  for (int t = 0; t < 4; t++) qf[t] = *(const bf16x8*)(qbase + t * 32 + hi * 8);

  f32x4 oacc[8];
#pragma unroll
  for (int i = 0; i < 8; i++) oacc[i] = fz;
  float m_[4] = {-1e30f, -1e30f, -1e30f, -1e30f};
  float l_[4] = {0.f, 0.f, 0.f, 0.f};

  const __bf16* kbase = Kk + (size_t)(b * NKV + kvh) * Ss * HD;
  const __bf16* vbase = Vt + (size_t)(b * NKV + kvh) * HD * Ss;

  const int kend = q0 + 64;
  for (int k0 = 0; k0 < kend; k0 += 32) {
    __syncthreads();
    // 16 chunks of 1KB: 0..7 = K tile (flat 8KB), 8..15 = Vt tile rows
#pragma unroll
    for (int c4 = 0; c4 < 4; ++c4) {
      int c = wave * 4 + c4;
      if (c < 8) {
        gload_lds16((const char*)(kbase + (size_t)k0 * HD) + c * 1024 + lane * 16,
                    (char*)Kl + c * 1024);
      } else {
        int cc = c - 8;
        int d = cc * 16 + srow;
        gload_lds16(vbase + (size_t)d * Ss + k0 + scol, (char*)Vl + cc * 1024);
      }
    }
    __syncthreads();

    // S = Q K^T for this wave's 16 rows x 32 keys
    f32x4 st[2];
#pragma unroll
    for (int t = 0; t < 2; t++) {
      st[t] = fz;
#pragma unroll
      for (int dc = 0; dc < 4; dc++) {
        bf16x8 kf = *(const bf16x8*)(Kl + (t * 16 + lr) * HD + dc * 32 + hi * 8);
        st[t] = mfma_bf16(qf[dc], kf, st[t]);
      }
    }

    // online softmax; row r=(hi*4+j) stats reduced across 16 lanes (xor 1,2,4,8)
    const int qrow0 = q0 + wave * 16 + hi * 4;
#pragma unroll
    for (int j = 0; j < 4; j++) {
      float s0 = st[0][j] * SCALE;
      float s1 = st[1][j] * SCALE;
      if (k0 + lr > qrow0 + j) s0 = -1e30f;
      if (k0 + 16 + lr > qrow0 + j) s1 = -1e30f;
      float mx = fmaxf(s0, s1);
      mx = fmaxf(mx, __shfl_xor(mx, 1, 64));
      mx = fmaxf(mx, __shfl_xor(mx, 2, 64));
      mx = fmaxf(mx, __shfl_xor(mx, 4, 64));
      mx = fmaxf(mx, __shfl_xor(mx, 8, 64));
      float mn = fmaxf(m_[j], mx);
      float al = __expf(m_[j] - mn);
      float p0 = __expf(s0 - mn), p1 = __expf(s1 - mn);
      float rs = p0 + p1;
      rs += __shfl_xor(rs, 1, 64);
      rs += __shfl_xor(rs, 2, 64);
      rs += __shfl_xor(rs, 4, 64);
      rs += __shfl_xor(rs, 8, 64);
      l_[j] = l_[j] * al + rs;
      m_[j] = mn;
#pragma unroll
      for (int dt = 0; dt < 8; dt++) oacc[dt][j] *= al;
      Pl[wave][(hi * 4 + j) * 32 + lr] = (__bf16)p0;
      Pl[wave][(hi * 4 + j) * 32 + 16 + lr] = (__bf16)p1;
    }
    __syncthreads();

    // O += P V : P is A-operand (rows = q), Vt rows are B-operand
    bf16x8 pf = *(const bf16x8*)(&Pl[wave][lr * 32 + hi * 8]);
#pragma unroll
    for (int dt = 0; dt < 8; dt++) {
      bf16x8 vf = *(const bf16x8*)(Vl + (dt * 16 + lr) * 32 + hi * 8);
      oacc[dt] = mfma_bf16(pf, vf, oacc[dt]);
    }
  }

#pragma unroll
  for (int dt = 0; dt < 8; dt++) {
#pragma unroll
    for (int j = 0; j < 4; j++) {
      int row = q0 + wave * 16 + hi * 4 + j;
      float o = oacc[dt][j] / l_[j];
      Oa[((size_t)(b * Ss) + row) * QSZ + h * HD + dt * 16 + lr] = (__bf16)o;
    }
  }
}

extern "C" void kernel_launch(void* const* d_in, const int* in_sizes, int n_in,
                              void* d_out, int out_size, void* d_ws, size_t ws_size,
                              hipStream_t stream) {
  const int* positions = (const int*)d_in[0];
  const float* hidden = (const float*)d_in[1];
  const float* w_qkv = (const float*)d_in[2];
  const float* b_qkv = (const float*)d_in[3];
  const float* w_o = (const float*)d_in[4];
  float* out = (float*)d_out;

  char* ws = (char*)d_ws;
  // layout (bytes): hs 33.5MB | wqkvT 50.3MB | woT 33.5MB | qkv 50.3MB |
  //                 q 33.5MB | k 8.4MB | vt 8.4MB        total ~218MB
  __bf16* hs = (__bf16*)(ws);
  __bf16* wqkvT = (__bf16*)(ws + 33554432);
  __bf16* woT = (__bf16*)(ws + 83886080);
  __bf16* qkv = (__bf16*)(ws + 117440512);
  __bf16* q = (__bf16*)(ws + 167772160);
  __bf16* k = (__bf16*)(ws + 201326592);
  __bf16* vt = (__bf16*)(ws + 209715200);
  __bf16* attn = hs;  // hs dead after gemm1; reuse for attention output

  f2b<<<2048, 256, 0, stream>>>(hidden, hs, (long)MTOT * HIDDEN / 4);
  transpose_conv<<<(HIDDEN / 64) * (QKV_N / 64), 256, 0, stream>>>(w_qkv, wqkvT, HIDDEN, QKV_N);
  transpose_conv<<<(QSZ / 64) * (HIDDEN / 64), 256, 0, stream>>>(w_o, woT, QSZ, HIDDEN);
  gemm_bt<<<(MTOT / 128) * (QKV_N / 128), 256, 0, stream>>>(hs, wqkvT, b_qkv, qkv,
                                                            MTOT, QKV_N, HIDDEN, 1);
  rope_qk<<<Bb * Ss, 256, 0, stream>>>(qkv, positions, q, k);
  vtrans<<<Bb * NKV * (Ss / 64), 256, 0, stream>>>(qkv, vt);
  attn_fwd<<<Bb * NH * (Ss / 64), 256, 0, stream>>>(q, k, vt, attn);
  gemm_bt<<<(MTOT / 128) * (QSZ / 128), 256, 0, stream>>>(attn, woT, nullptr, out,
                                                          MTOT, QSZ, QSZ, 0);
}

// Round 2
// 910.079 us; speedup vs baseline: 1.1914x; 1.1914x over previous
//
#include <hip/hip_runtime.h>
#include <hip/hip_bf16.h>
#include <math.h>

#define HIDDEN 4096
#define NH 32
#define NKV 8
#define HD 128
#define QSZ 4096
#define KVSZ 1024
#define QKV_N 6144
#define Bb 2
#define Ss 2048
#define MTOT 4096   // B*S
#define SCALE 0.08838834764831845f

typedef __attribute__((ext_vector_type(8))) __bf16 bf16x8;
typedef __attribute__((ext_vector_type(4))) __bf16 bf16x4;
typedef __attribute__((ext_vector_type(4))) float f32x4;

__device__ __forceinline__ f32x4 mfma_bf16(bf16x8 a, bf16x8 b, f32x4 c) {
  return __builtin_amdgcn_mfma_f32_16x16x32_bf16(a, b, c, 0, 0, 0);
}

// global -> LDS direct copy, 16B per lane. LDS dest is wave-uniform base;
// lane l lands at dst + l*16. Global src is per-lane.
__device__ __forceinline__ void gload_lds16(const void* g, void* l) {
  __builtin_amdgcn_global_load_lds((const __attribute__((address_space(1))) void*)g,
                                   (__attribute__((address_space(3))) void*)l, 16, 0, 0);
}

// ---------------- elementwise f32 -> bf16 (vectorized) ----------------
__global__ __launch_bounds__(256) void f2b(const float* __restrict__ in,
                                           __bf16* __restrict__ out, long n4) {
  for (long i = (long)blockIdx.x * blockDim.x + threadIdx.x; i < n4;
       i += (long)gridDim.x * blockDim.x) {
    float4 v = ((const float4*)in)[i];
    bf16x4 o = {(__bf16)v.x, (__bf16)v.y, (__bf16)v.z, (__bf16)v.w};
    ((bf16x4*)out)[i] = o;
  }
}

// ---------------- transpose + convert: w[K][N] f32 -> wT[N][K] bf16 ----------------
__global__ __launch_bounds__(256) void transpose_conv(const float* __restrict__ w,
                                                      __bf16* __restrict__ wT,
                                                      int K, int N) {
  __shared__ __bf16 tile[64][65];
  int nb = N >> 6;
  int kt = blockIdx.x / nb, nt = blockIdx.x % nb;
  for (int i = threadIdx.x; i < 64 * 64; i += 256) {
    int kl = i >> 6, nl = i & 63;
    tile[kl][nl] = (__bf16)w[(size_t)(kt * 64 + kl) * N + (nt * 64 + nl)];
  }
  __syncthreads();
  for (int i = threadIdx.x; i < 64 * 64; i += 256) {
    int nl = i >> 6, kl = i & 63;
    wT[(size_t)(nt * 64 + nl) * K + (kt * 64 + kl)] = tile[kl][nl];
  }
}

// ---------------- GEMM: C[M][N] = A[M][K] * Bt[N][K]^T (+bias) ----------------
// 128x128 tile, BK=32, 4 waves (2x2 quadrants of 64x64), 16x16x32 bf16 MFMA.
__global__ __launch_bounds__(256) void gemm_bt(const __bf16* __restrict__ A,
                                               const __bf16* __restrict__ Bt,
                                               const float* __restrict__ bias,
                                               void* __restrict__ Cout,
                                               int M, int N, int K, int out_bf16) {
  __shared__ __bf16 As[128 * 32];
  __shared__ __bf16 Bs[128 * 32];
  const int tid = threadIdx.x;
  const int wave = tid >> 6, lane = tid & 63;
  const int nbn = N >> 7;
  const int bm = blockIdx.x / nbn, bn = blockIdx.x % nbn;
  const int m0 = bm << 7, n0 = bn << 7;
  const int lr = lane & 15, hi = lane >> 4;
  const int srow = lane >> 2, scol = (lane & 3) << 3;

  const __bf16* gA = A + (size_t)(m0 + srow) * K + scol;
  const __bf16* gB = Bt + (size_t)(n0 + srow) * K + scol;
  __bf16* lA = As + wave * 1024;  // wave stages rows [32w, 32w+32)
  __bf16* lB = Bs + wave * 1024;

  const f32x4 fz = {0.f, 0.f, 0.f, 0.f};
  f32x4 acc[4][4];
#pragma unroll
  for (int i = 0; i < 4; i++)
#pragma unroll
    for (int j = 0; j < 4; j++) acc[i][j] = fz;

  const int mrow = (wave >> 1) * 64, ncol = (wave & 1) * 64;

  for (int k0 = 0; k0 < K; k0 += 32) {
    __syncthreads();
    gload_lds16(gA + (size_t)(wave * 32) * K + k0, lA);
    gload_lds16(gA + (size_t)(wave * 32 + 16) * K + k0, lA + 512);
    gload_lds16(gB + (size_t)(wave * 32) * K + k0, lB);
    gload_lds16(gB + (size_t)(wave * 32 + 16) * K + k0, lB + 512);
    __syncthreads();
    bf16x8 af[4], bfr[4];
#pragma unroll
    for (int i = 0; i < 4; i++)
      af[i] = *(const bf16x8*)(As + (mrow + i * 16 + lr) * 32 + hi * 8);
#pragma unroll
    for (int i = 0; i < 4; i++)
      bfr[i] = *(const bf16x8*)(Bs + (ncol + i * 16 + lr) * 32 + hi * 8);
#pragma unroll
    for (int i = 0; i < 4; i++)
#pragma unroll
      for (int j = 0; j < 4; j++) acc[i][j] = mfma_bf16(af[i], bfr[j], acc[i][j]);
  }

  // epilogue: D[row=(lane>>4)*4+r][col=lane&15] per 16x16 tile (verified m89 layout)
#pragma unroll
  for (int i = 0; i < 4; i++) {
    int row_base = m0 + mrow + i * 16 + hi * 4;
#pragma unroll
    for (int j = 0; j < 4; j++) {
      int col = n0 + ncol + j * 16 + lr;
      float bv = bias ? bias[col] : 0.f;
#pragma unroll
      for (int r = 0; r < 4; r++) {
        int row = row_base + r;
        float v = acc[i][j][r] + bv;
        if (out_bf16)
          ((__bf16*)Cout)[(size_t)row * N + col] = (__bf16)v;
        else
          ((float*)Cout)[(size_t)row * N + col] = v;
      }
    }
  }
}

// ---------------- RoPE for q and k ----------------
__global__ __launch_bounds__(256) void rope_qk(const __bf16* __restrict__ qkv,
                                               const int* __restrict__ pos,
                                               __bf16* __restrict__ Qo,
                                               __bf16* __restrict__ Ko) {
  int bs = blockIdx.x;
  int b = bs / Ss, s = bs % Ss;
  float p = (float)pos[s];
  const __bf16* src = qkv + (size_t)bs * QKV_N;
  for (int t = threadIdx.x; t < (NH + NKV) * 64; t += 256) {
    int head = t >> 6, i = t & 63;
    float inv = powf(10000.f, -(float)i * (1.f / 64.f));
    float sn, cs;
    sincosf(p * inv, &sn, &cs);
    if (head < NH) {
      float x1 = (float)src[head * HD + i];
      float x2 = (float)src[head * HD + i + 64];
      __bf16* dst = Qo + ((size_t)(b * NH + head) * Ss + s) * HD;
      dst[i] = (__bf16)(x1 * cs - x2 * sn);
      dst[i + 64] = (__bf16)(x2 * cs + x1 * sn);
    } else {
      int kh = head - NH;
      float x1 = (float)src[QSZ + kh * HD + i];
      float x2 = (float)src[QSZ + kh * HD + i + 64];
      __bf16* dst = Ko + ((size_t)(b * NKV + kh) * Ss + s) * HD;
      dst[i] = (__bf16)(x1 * cs - x2 * sn);
      dst[i + 64] = (__bf16)(x2 * cs + x1 * sn);
    }
  }
}

// ---------------- V transpose: qkv v-part -> Vt[B][KVH][D][S] ----------------
__global__ __launch_bounds__(256) void vtrans(const __bf16* __restrict__ qkv,
                                              __bf16* __restrict__ Vt) {
  __shared__ __bf16 tile[128][65];
  int bid = blockIdx.x;
  int st_ = bid & 31;
  int kvh = (bid >> 5) & 7;
  int b = bid >> 8;
  int s0 = st_ * 64;
  const __bf16* src = qkv + (size_t)(b * Ss) * QKV_N + (QSZ + KVSZ) + kvh * HD;
  for (int i = threadIdx.x; i < 64 * 128; i += 256) {
    int sl = i >> 7, d = i & 127;
    tile[d][sl] = src[(size_t)(s0 + sl) * QKV_N + d];
  }
  __syncthreads();
  __bf16* dst = Vt + (size_t)(b * NKV + kvh) * HD * Ss;
  for (int i = threadIdx.x; i < 64 * 128; i += 256) {
    int dl = i >> 6, sl = i & 63;
    dst[(size_t)dl * Ss + s0 + sl] = tile[dl][sl];
  }
}

// ---------------- causal flash attention (v2) ----------------
// grid: B*NH*(S/64); block 256 = 4 waves, each wave owns 16 q rows.
// KVBLK=64. All LDS tiles XOR-swizzled in 16B slots (T2); staging via
// global_load_lds with pre-swizzled GLOBAL source (rule 21: linear LDS dest,
// inverse-swizzled source, swizzled read -- same involution on both sides).
__global__ __launch_bounds__(256) void attn_fwd(const __bf16* __restrict__ Q,
                                                const __bf16* __restrict__ Kk,
                                                const __bf16* __restrict__ Vt,
                                                __bf16* __restrict__ Oa) {
  __shared__ __bf16 Kl[64 * 128];   // [64 keys][128 d], 16 slots/row, slot^=(row&15)
  __shared__ __bf16 Vl[128 * 64];   // [128 d][64 keys], 8 slots/row, slot^=(row&7)
  __shared__ __bf16 Pl[4][16 * 64]; // per-wave [16 q][64 keys], 8 slots/row
  const int tid = threadIdx.x, wave = tid >> 6, lane = tid & 63;
  const int nqb = Ss / 64;
  const int bid = blockIdx.x;
  const int b = bid / (NH * nqb);
  const int h = (bid / nqb) % NH;
  const int qb = (nqb - 1) - (bid % nqb);  // heavy (large-q0) blocks dispatch first
  const int q0 = qb * 64;
  const int kvh = h >> 2;
  const int lr = lane & 15, hi = lane >> 4;
  const f32x4 fz = {0.f, 0.f, 0.f, 0.f};

  const __bf16* qbase = Q + ((size_t)(b * NH + h) * Ss + q0 + wave * 16 + lr) * HD;
  bf16x8 qf[4];
#pragma unroll
  for (int dc = 0; dc < 4; dc++) qf[dc] = *(const bf16x8*)(qbase + dc * 32 + hi * 8);

  f32x4 oacc[8];
#pragma unroll
  for (int i = 0; i < 8; i++) oacc[i] = fz;
  float m_[4] = {-1e30f, -1e30f, -1e30f, -1e30f};
  float l_[4] = {0.f, 0.f, 0.f, 0.f};

  const __bf16* kbase = Kk + (size_t)(b * NKV + kvh) * Ss * HD;
  const __bf16* vbase = Vt + (size_t)(b * NKV + kvh) * HD * Ss;

  // per-lane staging coords (16 chunks of 1KB per tile, wave stages 8 chunks)
  const int krow_st = lane >> 4;  // + c*4
  const int kslot = lane & 15;
  const int vrow_st = lane >> 3;  // + cc*8
  const int vslot = lane & 7;

  const int kend = q0 + 64;
  for (int k0 = 0; k0 < kend; k0 += 64) {
    __syncthreads();  // prev chunk's LDS reads done before overwrite
#pragma unroll
    for (int i = 0; i < 8; i++) {
      int c = wave * 8 + i;
      if (c < 16) {
        int r = c * 4 + krow_st;  // key row 0..63
        gload_lds16(kbase + (size_t)(k0 + r) * HD + ((kslot ^ (r & 15)) << 3),
                    (char*)Kl + c * 1024);
      } else {
        int cc = c - 16;
        int r = cc * 8 + vrow_st;  // d row 0..127
        gload_lds16(vbase + (size_t)r * Ss + k0 + ((vslot ^ (r & 7)) << 3),
                    (char*)Vl + cc * 1024);
      }
    }
    __syncthreads();  // stage complete (vmcnt drained by barrier semantics)

    // S = Q K^T : 4 key tiles x 4 k-slices
    f32x4 st[4];
#pragma unroll
    for (int t = 0; t < 4; t++) {
      st[t] = fz;
#pragma unroll
      for (int dc = 0; dc < 4; dc++) {
        const bf16x8 kf = *(const bf16x8*)((const char*)Kl + (t * 16 + lr) * 256 +
                                           (((dc * 4 + hi) ^ lr) << 4));
        st[t] = mfma_bf16(qf[dc], kf, st[t]);
      }
    }

    const bool diag = (k0 == q0);  // only last chunk needs causal mask
    float sv[4][4], mx4[4];
#pragma unroll
    for (int j = 0; j < 4; j++) {
#pragma unroll
      for (int t = 0; t < 4; t++) {
        float s = st[t][j] * SCALE;
        if (diag && (t * 16 + lr > wave * 16 + hi * 4 + j)) s = -1e30f;
        sv[j][t] = s;
      }
      float mx = fmaxf(fmaxf(sv[j][0], sv[j][1]), fmaxf(sv[j][2], sv[j][3]));
      mx = fmaxf(mx, __shfl_xor(mx, 1, 64));
      mx = fmaxf(mx, __shfl_xor(mx, 2, 64));
      mx = fmaxf(mx, __shfl_xor(mx, 4, 64));
      mx = fmaxf(mx, __shfl_xor(mx, 8, 64));
      mx4[j] = mx;
    }
    // defer-max (T13): rescale O only when running max grows by > 8
    bool need = (mx4[0] > m_[0] + 8.f) || (mx4[1] > m_[1] + 8.f) ||
                (mx4[2] > m_[2] + 8.f) || (mx4[3] > m_[3] + 8.f);
    if (__any(need)) {
#pragma unroll
      for (int j = 0; j < 4; j++) {
        float mn = fmaxf(m_[j], mx4[j]);
        float al = __expf(m_[j] - mn);
        l_[j] *= al;
        m_[j] = mn;
#pragma unroll
        for (int dt = 0; dt < 8; dt++) oacc[dt][j] *= al;
      }
    }

    char* pw = (char*)Pl + wave * 2048;  // per-wave P: no barrier needed
#pragma unroll
    for (int j = 0; j < 4; j++) {
      int rowp = hi * 4 + j;
      float rs = 0.f;
#pragma unroll
      for (int t = 0; t < 4; t++) {
        float p = __expf(sv[j][t] - m_[j]);
        rs += p;
        int slot = t * 2 + (lr >> 3);
        *(__bf16*)(pw + rowp * 128 + ((slot ^ (rowp & 7)) << 4) + (lr & 7) * 2) =
            (__bf16)p;
      }
      rs += __shfl_xor(rs, 1, 64);
      rs += __shfl_xor(rs, 2, 64);
      rs += __shfl_xor(rs, 4, 64);
      rs += __shfl_xor(rs, 8, 64);
      l_[j] += rs;
    }

    // O += P V
    bf16x8 pf[2];
#pragma unroll
    for (int kf_ = 0; kf_ < 2; kf_++)
      pf[kf_] = *(const bf16x8*)(pw + lr * 128 + (((kf_ * 4 + hi) ^ (lr & 7)) << 4));
#pragma unroll
    for (int dt = 0; dt < 8; dt++) {
#pragma unroll
      for (int kf_ = 0; kf_ < 2; kf_++) {
        const bf16x8 vf = *(const bf16x8*)((const char*)Vl + (dt * 16 + lr) * 128 +
                                           (((kf_ * 4 + hi) ^ (lr & 7)) << 4));
        oacc[dt] = mfma_bf16(pf[kf_], vf, oacc[dt]);
      }
    }
  }

#pragma unroll
  for (int dt = 0; dt < 8; dt++) {
#pragma unroll
    for (int j = 0; j < 4; j++) {
      int row = q0 + wave * 16 + hi * 4 + j;
      float o = oacc[dt][j] / l_[j];
      Oa[((size_t)(b * Ss) + row) * QSZ + h * HD + dt * 16 + lr] = (__bf16)o;
    }
  }
}

extern "C" void kernel_launch(void* const* d_in, const int* in_sizes, int n_in,
                              void* d_out, int out_size, void* d_ws, size_t ws_size,
                              hipStream_t stream) {
  const int* positions = (const int*)d_in[0];
  const float* hidden = (const float*)d_in[1];
  const float* w_qkv = (const float*)d_in[2];
  const float* b_qkv = (const float*)d_in[3];
  const float* w_o = (const float*)d_in[4];
  float* out = (float*)d_out;

  char* ws = (char*)d_ws;
  // layout (bytes): hs 33.5MB | wqkvT 50.3MB | woT 33.5MB | qkv 50.3MB |
  //                 q 33.5MB | k 8.4MB | vt 8.4MB        total ~218MB
  __bf16* hs = (__bf16*)(ws);
  __bf16* wqkvT = (__bf16*)(ws + 33554432);
  __bf16* woT = (__bf16*)(ws + 83886080);
  __bf16* qkv = (__bf16*)(ws + 117440512);
  __bf16* q = (__bf16*)(ws + 167772160);
  __bf16* k = (__bf16*)(ws + 201326592);
  __bf16* vt = (__bf16*)(ws + 209715200);
  __bf16* attn = hs;  // hs dead after gemm1; reuse for attention output

  f2b<<<2048, 256, 0, stream>>>(hidden, hs, (long)MTOT * HIDDEN / 4);
  transpose_conv<<<(HIDDEN / 64) * (QKV_N / 64), 256, 0, stream>>>(w_qkv, wqkvT, HIDDEN, QKV_N);
  transpose_conv<<<(QSZ / 64) * (HIDDEN / 64), 256, 0, stream>>>(w_o, woT, QSZ, HIDDEN);
  gemm_bt<<<(MTOT / 128) * (QKV_N / 128), 256, 0, stream>>>(hs, wqkvT, b_qkv, qkv,
                                                            MTOT, QKV_N, HIDDEN, 1);
  rope_qk<<<Bb * Ss, 256, 0, stream>>>(qkv, positions, q, k);
  vtrans<<<Bb * NKV * (Ss / 64), 256, 0, stream>>>(qkv, vt);
  attn_fwd<<<Bb * NH * (Ss / 64), 256, 0, stream>>>(q, k, vt, attn);
  gemm_bt<<<(MTOT / 128) * (QSZ / 128), 256, 0, stream>>>(attn, woT, nullptr, out,
                                                          MTOT, QSZ, QSZ, 0);
}

// Round 3
// 794.141 us; speedup vs baseline: 1.3653x; 1.1460x over previous
//
#include <hip/hip_runtime.h>
#include <hip/hip_bf16.h>
#include <math.h>

#define HIDDEN 4096
#define NH 32
#define NKV 8
#define HD 128
#define QSZ 4096
#define KVSZ 1024
#define QKV_N 6144
#define Bb 2
#define Ss 2048
#define MTOT 4096   // B*S
#define SCALE 0.08838834764831845f

typedef __attribute__((ext_vector_type(8))) __bf16 bf16x8;
typedef __attribute__((ext_vector_type(4))) __bf16 bf16x4;
typedef __attribute__((ext_vector_type(4))) float f32x4;

__device__ __forceinline__ f32x4 mfma_bf16(bf16x8 a, bf16x8 b, f32x4 c) {
  return __builtin_amdgcn_mfma_f32_16x16x32_bf16(a, b, c, 0, 0, 0);
}

// global -> LDS direct copy, 16B per lane. LDS dest is wave-uniform base;
// lane l lands at dst + l*16. Global src is per-lane.
__device__ __forceinline__ void gload_lds16(const void* g, void* l) {
  __builtin_amdgcn_global_load_lds((const __attribute__((address_space(1))) void*)g,
                                   (__attribute__((address_space(3))) void*)l, 16, 0, 0);
}

// ---------------- elementwise f32 -> bf16 (vectorized) ----------------
__global__ __launch_bounds__(256) void f2b(const float* __restrict__ in,
                                           __bf16* __restrict__ out, long n4) {
  for (long i = (long)blockIdx.x * blockDim.x + threadIdx.x; i < n4;
       i += (long)gridDim.x * blockDim.x) {
    float4 v = ((const float4*)in)[i];
    bf16x4 o = {(__bf16)v.x, (__bf16)v.y, (__bf16)v.z, (__bf16)v.w};
    ((bf16x4*)out)[i] = o;
  }
}

// ---------------- transpose + convert: w[K][N] f32 -> wT[N][K] bf16 ----------------
__global__ __launch_bounds__(256) void transpose_conv(const float* __restrict__ w,
                                                      __bf16* __restrict__ wT,
                                                      int K, int N) {
  __shared__ __bf16 tile[64][65];
  int nb = N >> 6;
  int kt = blockIdx.x / nb, nt = blockIdx.x % nb;
  for (int i = threadIdx.x; i < 64 * 64; i += 256) {
    int kl = i >> 6, nl = i & 63;
    tile[kl][nl] = (__bf16)w[(size_t)(kt * 64 + kl) * N + (nt * 64 + nl)];
  }
  __syncthreads();
  for (int i = threadIdx.x; i < 64 * 64; i += 256) {
    int nl = i >> 6, kl = i & 63;
    wT[(size_t)(nt * 64 + nl) * K + (kt * 64 + kl)] = tile[kl][nl];
  }
}

// ---------------- GEMM: C[M][N] = A[M][K] * Bt[N][K]^T (+bias) ----------------
// 128x128 tile, BK=32, 4 waves (2x2 quadrants of 64x64), 16x16x32 bf16 MFMA.
__global__ __launch_bounds__(256) void gemm_bt(const __bf16* __restrict__ A,
                                               const __bf16* __restrict__ Bt,
                                               const float* __restrict__ bias,
                                               void* __restrict__ Cout,
                                               int M, int N, int K, int out_bf16) {
  __shared__ __bf16 As[128 * 32];
  __shared__ __bf16 Bs[128 * 32];
  const int tid = threadIdx.x;
  const int wave = tid >> 6, lane = tid & 63;
  const int nbn = N >> 7;
  const int bm = blockIdx.x / nbn, bn = blockIdx.x % nbn;
  const int m0 = bm << 7, n0 = bn << 7;
  const int lr = lane & 15, hi = lane >> 4;
  const int srow = lane >> 2, scol = (lane & 3) << 3;

  const __bf16* gA = A + (size_t)(m0 + srow) * K + scol;
  const __bf16* gB = Bt + (size_t)(n0 + srow) * K + scol;
  __bf16* lA = As + wave * 1024;  // wave stages rows [32w, 32w+32)
  __bf16* lB = Bs + wave * 1024;

  const f32x4 fz = {0.f, 0.f, 0.f, 0.f};
  f32x4 acc[4][4];
#pragma unroll
  for (int i = 0; i < 4; i++)
#pragma unroll
    for (int j = 0; j < 4; j++) acc[i][j] = fz;

  const int mrow = (wave >> 1) * 64, ncol = (wave & 1) * 64;

  for (int k0 = 0; k0 < K; k0 += 32) {
    __syncthreads();
    gload_lds16(gA + (size_t)(wave * 32) * K + k0, lA);
    gload_lds16(gA + (size_t)(wave * 32 + 16) * K + k0, lA + 512);
    gload_lds16(gB + (size_t)(wave * 32) * K + k0, lB);
    gload_lds16(gB + (size_t)(wave * 32 + 16) * K + k0, lB + 512);
    __syncthreads();
    bf16x8 af[4], bfr[4];
#pragma unroll
    for (int i = 0; i < 4; i++)
      af[i] = *(const bf16x8*)(As + (mrow + i * 16 + lr) * 32 + hi * 8);
#pragma unroll
    for (int i = 0; i < 4; i++)
      bfr[i] = *(const bf16x8*)(Bs + (ncol + i * 16 + lr) * 32 + hi * 8);
#pragma unroll
    for (int i = 0; i < 4; i++)
#pragma unroll
      for (int j = 0; j < 4; j++) acc[i][j] = mfma_bf16(af[i], bfr[j], acc[i][j]);
  }

  // epilogue: D[row=(lane>>4)*4+r][col=lane&15] per 16x16 tile (verified m89 layout)
#pragma unroll
  for (int i = 0; i < 4; i++) {
    int row_base = m0 + mrow + i * 16 + hi * 4;
#pragma unroll
    for (int j = 0; j < 4; j++) {
      int col = n0 + ncol + j * 16 + lr;
      float bv = bias ? bias[col] : 0.f;
#pragma unroll
      for (int r = 0; r < 4; r++) {
        int row = row_base + r;
        float v = acc[i][j][r] + bv;
        if (out_bf16)
          ((__bf16*)Cout)[(size_t)row * N + col] = (__bf16)v;
        else
          ((float*)Cout)[(size_t)row * N + col] = v;
      }
    }
  }
}

// ---------------- RoPE for q and k ----------------
__global__ __launch_bounds__(256) void rope_qk(const __bf16* __restrict__ qkv,
                                               const int* __restrict__ pos,
                                               __bf16* __restrict__ Qo,
                                               __bf16* __restrict__ Ko) {
  int bs = blockIdx.x;
  int b = bs / Ss, s = bs % Ss;
  float p = (float)pos[s];
  const __bf16* src = qkv + (size_t)bs * QKV_N;
  for (int t = threadIdx.x; t < (NH + NKV) * 64; t += 256) {
    int head = t >> 6, i = t & 63;
    // inv_freq = 10000^(-i/64) = 2^(-i*log2(10000)/64)
    float inv = exp2f((float)i * (-13.287712379549449f / 64.f));
    float sn, cs;
    sincosf(p * inv, &sn, &cs);
    if (head < NH) {
      float x1 = (float)src[head * HD + i];
      float x2 = (float)src[head * HD + i + 64];
      __bf16* dst = Qo + ((size_t)(b * NH + head) * Ss + s) * HD;
      dst[i] = (__bf16)(x1 * cs - x2 * sn);
      dst[i + 64] = (__bf16)(x2 * cs + x1 * sn);
    } else {
      int kh = head - NH;
      float x1 = (float)src[QSZ + kh * HD + i];
      float x2 = (float)src[QSZ + kh * HD + i + 64];
      __bf16* dst = Ko + ((size_t)(b * NKV + kh) * Ss + s) * HD;
      dst[i] = (__bf16)(x1 * cs - x2 * sn);
      dst[i + 64] = (__bf16)(x2 * cs + x1 * sn);
    }
  }
}

// ---------------- V transpose: qkv v-part -> Vt[B][KVH][D][S] ----------------
__global__ __launch_bounds__(256) void vtrans(const __bf16* __restrict__ qkv,
                                              __bf16* __restrict__ Vt) {
  __shared__ __bf16 tile[128][65];
  int bid = blockIdx.x;
  int st_ = bid & 31;
  int kvh = (bid >> 5) & 7;
  int b = bid >> 8;
  int s0 = st_ * 64;
  const __bf16* src = qkv + (size_t)(b * Ss) * QKV_N + (QSZ + KVSZ) + kvh * HD;
  for (int i = threadIdx.x; i < 64 * 128; i += 256) {
    int sl = i >> 7, d = i & 127;
    tile[d][sl] = src[(size_t)(s0 + sl) * QKV_N + d];
  }
  __syncthreads();
  __bf16* dst = Vt + (size_t)(b * NKV + kvh) * HD * Ss;
  for (int i = threadIdx.x; i < 64 * 128; i += 256) {
    int dl = i >> 6, sl = i & 63;
    dst[(size_t)dl * Ss + s0 + sl] = tile[dl][sl];
  }
}

// ---------------- causal flash attention (v3) ----------------
// grid: B*NH*(S/64); block 256 = 4 waves, each wave owns 16 q rows.
// KVBLK=64, double-buffered K/V (T3-minimum 2-phase: stage(c+1) issued before
// compute(c), single __syncthreads per chunk drains vmcnt AFTER compute).
// Swapped QK^T: st = mfma(K,Q) -> lane (lr,hi) holds 16 scores of q-row lr
// (keys 16t+4hi+r). Softmax state m,l = one scalar per lane; row reduce =
// in-lane tree + shfl_xor(16) + shfl_xor(32). P redistributed to PV A-frag
// layout via swizzled LDS round-trip (4x ds_write_b64 + 2x ds_read_b128).
// O accumulator rows = hi*4+r, so rescale/divide factors come via 4 __shfl.
__global__ __launch_bounds__(256) void attn_fwd(const __bf16* __restrict__ Q,
                                                const __bf16* __restrict__ Kk,
                                                const __bf16* __restrict__ Vt,
                                                __bf16* __restrict__ Oa) {
  __shared__ __bf16 Kl[2][64 * 128];   // [64 keys][128 d], 16B slots ^= (row&15)
  __shared__ __bf16 Vl[2][128 * 64];   // [128 d][64 keys], 16B slots ^= (row&7)
  __shared__ __bf16 Pl[4][16 * 64];    // per-wave [16 q][64 keys], slots ^= (row&7)
  const int tid = threadIdx.x, wave = tid >> 6, lane = tid & 63;
  const int nqb = Ss / 64;
  const int bid = blockIdx.x;
  const int b = bid / (NH * nqb);
  const int h = (bid / nqb) % NH;
  const int qb = (nqb - 1) - (bid % nqb);  // heavy blocks early in dispatch
  const int q0 = qb * 64;
  const int kvh = h >> 2;
  const int lr = lane & 15, hi = lane >> 4;
  const f32x4 fz = {0.f, 0.f, 0.f, 0.f};

  const __bf16* qbase = Q + ((size_t)(b * NH + h) * Ss + q0 + wave * 16 + lr) * HD;
  bf16x8 qf[4];
#pragma unroll
  for (int dc = 0; dc < 4; dc++) qf[dc] = *(const bf16x8*)(qbase + dc * 32 + hi * 8);

  f32x4 oacc[8];
#pragma unroll
  for (int i = 0; i < 8; i++) oacc[i] = fz;
  float m_ = -1e30f, l_ = 0.f;

  const __bf16* kbase = Kk + (size_t)(b * NKV + kvh) * Ss * HD;
  const __bf16* vbase = Vt + (size_t)(b * NKV + kvh) * HD * Ss;

  const int nc = qb + 1;  // chunks of 64 keys

  auto STAGE = [&](int c, int buf) {
    const int k0 = c * 64;
#pragma unroll
    for (int i = 0; i < 8; i++) {
      int cidx = wave * 8 + i;
      if (cidx < 16) {
        int r = cidx * 4 + (lane >> 4);  // key row 0..63
        gload_lds16(kbase + (size_t)(k0 + r) * HD + (((lane & 15) ^ (r & 15)) << 3),
                    (char*)Kl[buf] + cidx * 1024);
      } else {
        int cc = cidx - 16;
        int r = cc * 8 + (lane >> 3);    // d row 0..127
        gload_lds16(vbase + (size_t)r * Ss + k0 + (((lane & 7) ^ (r & 7)) << 3),
                    (char*)Vl[buf] + cc * 1024);
      }
    }
  };

  STAGE(0, 0);
  __syncthreads();
  int cur = 0;
  char* pw = (char*)Pl[wave];

  for (int c = 0; c < nc; ++c) {
    if (c + 1 < nc) STAGE(c + 1, cur ^ 1);  // prefetch lands during compute

    const char* Kb = (const char*)Kl[cur];
    const char* Vb = (const char*)Vl[cur];

    // S^T = K Q^T : lane (lr,hi) gets keys 16t+4hi+r of q-row lr
    f32x4 st[4];
#pragma unroll
    for (int t = 0; t < 4; t++) {
      st[t] = fz;
#pragma unroll
      for (int dc = 0; dc < 4; dc++) {
        const bf16x8 kf = *(const bf16x8*)(Kb + (t * 16 + lr) * 256 +
                                           (((dc * 4 + hi) ^ lr) << 4));
        st[t] = mfma_bf16(kf, qf[dc], st[t]);
      }
    }

    const bool diag = (c == nc - 1);
    float s[4][4];
    float mx = -1e30f;
#pragma unroll
    for (int t = 0; t < 4; t++)
#pragma unroll
      for (int r = 0; r < 4; r++) {
        float v = st[t][r] * SCALE;
        if (diag && (t * 16 + hi * 4 + r > wave * 16 + lr)) v = -1e30f;
        s[t][r] = v;
        mx = fmaxf(mx, v);
      }
    mx = fmaxf(mx, __shfl_xor(mx, 16, 64));
    mx = fmaxf(mx, __shfl_xor(mx, 32, 64));

    // defer-max (T13): O-rescale only when running max grows by > 8
    if (__any(mx > m_ + 8.f)) {
      float mn = fmaxf(m_, mx);
      float al = __expf(m_ - mn);
      l_ *= al;
      m_ = mn;
      float alr[4];
#pragma unroll
      for (int r = 0; r < 4; r++) alr[r] = __shfl(al, hi * 4 + r, 64);
#pragma unroll
      for (int dt = 0; dt < 8; dt++)
#pragma unroll
        for (int r = 0; r < 4; r++) oacc[dt][r] *= alr[r];
    }

    float rs = 0.f;
#pragma unroll
    for (int t = 0; t < 4; t++) {
      float p0 = __expf(s[t][0] - m_), p1 = __expf(s[t][1] - m_);
      float p2 = __expf(s[t][2] - m_), p3 = __expf(s[t][3] - m_);
      rs += (p0 + p1) + (p2 + p3);
      bf16x4 pv = {(__bf16)p0, (__bf16)p1, (__bf16)p2, (__bf16)p3};
      // keys 16t+4hi+0..3 of row lr: slot16=(2t+(hi>>1))^(lr&7), half=(hi&1)*8
      *(bf16x4*)(pw + lr * 128 + (((2 * t + (hi >> 1)) ^ (lr & 7)) << 4) +
                 (hi & 1) * 8) = pv;
    }
    rs += __shfl_xor(rs, 16, 64);
    rs += __shfl_xor(rs, 32, 64);
    l_ += rs;

    // PV: pf = P[q=lr][keys 32kf+8hi..], vf = Vt[d=dt*16+lr][keys ...]
    bf16x8 pf[2];
#pragma unroll
    for (int kf_ = 0; kf_ < 2; kf_++)
      pf[kf_] = *(const bf16x8*)(pw + lr * 128 + (((4 * kf_ + hi) ^ (lr & 7)) << 4));
#pragma unroll
    for (int dt = 0; dt < 8; dt++) {
#pragma unroll
      for (int kf_ = 0; kf_ < 2; kf_++) {
        const bf16x8 vf = *(const bf16x8*)(Vb + (dt * 16 + lr) * 128 +
                                           (((kf_ * 4 + hi) ^ (lr & 7)) << 4));
        oacc[dt] = mfma_bf16(pf[kf_], vf, oacc[dt]);
      }
    }

    __syncthreads();  // drains prefetch vmcnt AFTER compute; guards buffer swap
    cur ^= 1;
  }

  float rl[4];
#pragma unroll
  for (int r = 0; r < 4; r++) rl[r] = __shfl(l_, hi * 4 + r, 64);
#pragma unroll
  for (int dt = 0; dt < 8; dt++) {
#pragma unroll
    for (int r = 0; r < 4; r++) {
      int row = q0 + wave * 16 + hi * 4 + r;
      Oa[((size_t)(b * Ss) + row) * QSZ + h * HD + dt * 16 + lr] =
          (__bf16)(oacc[dt][r] / rl[r]);
    }
  }
}

extern "C" void kernel_launch(void* const* d_in, const int* in_sizes, int n_in,
                              void* d_out, int out_size, void* d_ws, size_t ws_size,
                              hipStream_t stream) {
  const int* positions = (const int*)d_in[0];
  const float* hidden = (const float*)d_in[1];
  const float* w_qkv = (const float*)d_in[2];
  const float* b_qkv = (const float*)d_in[3];
  const float* w_o = (const float*)d_in[4];
  float* out = (float*)d_out;

  char* ws = (char*)d_ws;
  // layout (bytes): hs 33.5MB | wqkvT 50.3MB | woT 33.5MB | qkv 50.3MB |
  //                 q 33.5MB | k 8.4MB | vt 8.4MB        total ~218MB
  __bf16* hs = (__bf16*)(ws);
  __bf16* wqkvT = (__bf16*)(ws + 33554432);
  __bf16* woT = (__bf16*)(ws + 83886080);
  __bf16* qkv = (__bf16*)(ws + 117440512);
  __bf16* q = (__bf16*)(ws + 167772160);
  __bf16* k = (__bf16*)(ws + 201326592);
  __bf16* vt = (__bf16*)(ws + 209715200);
  __bf16* attn = hs;  // hs dead after gemm1; reuse for attention output

  f2b<<<2048, 256, 0, stream>>>(hidden, hs, (long)MTOT * HIDDEN / 4);
  transpose_conv<<<(HIDDEN / 64) * (QKV_N / 64), 256, 0, stream>>>(w_qkv, wqkvT, HIDDEN, QKV_N);
  transpose_conv<<<(QSZ / 64) * (HIDDEN / 64), 256, 0, stream>>>(w_o, woT, QSZ, HIDDEN);
  gemm_bt<<<(MTOT / 128) * (QKV_N / 128), 256, 0, stream>>>(hs, wqkvT, b_qkv, qkv,
                                                            MTOT, QKV_N, HIDDEN, 1);
  rope_qk<<<Bb * Ss, 256, 0, stream>>>(qkv, positions, q, k);
  vtrans<<<Bb * NKV * (Ss / 64), 256, 0, stream>>>(qkv, vt);
  attn_fwd<<<Bb * NH * (Ss / 64), 256, 0, stream>>>(q, k, vt, attn);
  gemm_bt<<<(MTOT / 128) * (QSZ / 128), 256, 0, stream>>>(attn, woT, nullptr, out,
                                                          MTOT, QSZ, QSZ, 0);
}

// Round 5
// 671.150 us; speedup vs baseline: 1.6155x; 1.1833x over previous
//
#include <hip/hip_runtime.h>
#include <hip/hip_bf16.h>
#include <math.h>

#define HIDDEN 4096
#define NH 32
#define NKV 8
#define HD 128
#define QSZ 4096
#define KVSZ 1024
#define QKV_N 6144
#define Bb 2
#define Ss 2048
#define MTOT 4096   // B*S
#define SCALE 0.08838834764831845f

typedef __attribute__((ext_vector_type(8))) __bf16 bf16x8;
typedef __attribute__((ext_vector_type(4))) __bf16 bf16x4;
typedef __attribute__((ext_vector_type(4))) float f32x4;

__device__ __forceinline__ f32x4 mfma_bf16(bf16x8 a, bf16x8 b, f32x4 c) {
  return __builtin_amdgcn_mfma_f32_16x16x32_bf16(a, b, c, 0, 0, 0);
}

// global -> LDS direct copy, 16B per lane. LDS dest is wave-uniform base;
// lane l lands at dst + l*16. Global src is per-lane.
__device__ __forceinline__ void gload_lds16(const void* g, void* l) {
  __builtin_amdgcn_global_load_lds((const __attribute__((address_space(1))) void*)g,
                                   (__attribute__((address_space(3))) void*)l, 16, 0, 0);
}

#define VM8() asm volatile("s_waitcnt vmcnt(8)" ::: "memory")
#define VM4() asm volatile("s_waitcnt vmcnt(4)" ::: "memory")
#define VM0() asm volatile("s_waitcnt vmcnt(0)" ::: "memory")
#define BAR() asm volatile("s_barrier" ::: "memory")

// ---------------- elementwise f32 -> bf16 (vectorized) ----------------
__global__ __launch_bounds__(256) void f2b(const float* __restrict__ in,
                                           __bf16* __restrict__ out, long n4) {
  for (long i = (long)blockIdx.x * blockDim.x + threadIdx.x; i < n4;
       i += (long)gridDim.x * blockDim.x) {
    float4 v = ((const float4*)in)[i];
    bf16x4 o = {(__bf16)v.x, (__bf16)v.y, (__bf16)v.z, (__bf16)v.w};
    ((bf16x4*)out)[i] = o;
  }
}

// ---------------- transpose + convert: w[K][N] f32 -> wT[N][K] bf16 ----------------
__global__ __launch_bounds__(256) void transpose_conv(const float* __restrict__ w,
                                                      __bf16* __restrict__ wT,
                                                      int K, int N) {
  __shared__ __bf16 tile[64][65];
  int nb = N >> 6;
  int kt = blockIdx.x / nb, nt = blockIdx.x % nb;
  for (int i = threadIdx.x; i < 64 * 64; i += 256) {
    int kl = i >> 6, nl = i & 63;
    tile[kl][nl] = (__bf16)w[(size_t)(kt * 64 + kl) * N + (nt * 64 + nl)];
  }
  __syncthreads();
  for (int i = threadIdx.x; i < 64 * 64; i += 256) {
    int nl = i >> 6, kl = i & 63;
    wT[(size_t)(nt * 64 + nl) * K + (kt * 64 + kl)] = tile[kl][nl];
  }
}

// ---------------- GEMM 256x256 deep-pipelined: C[M][N] = A * Bt^T (+bias) ----------
// 8 waves (2M x 4N), per-wave 128x64 output. BK=32. Ring of 4 LDS buffers
// (32KB each: A 256x32 + B 256x32, bf16), staged 3 K-steps ahead via
// global_load_lds (4 loads/wave/step). Boundary: s_waitcnt vmcnt(8) + raw
// s_barrier -- per-wave FIFO vmcnt retires exactly step-t's 4 loads; barrier
// publishes all waves' LDS writes (T4: counted, never 0 in main loop).
// LDS 16B-slot swizzle: slot ^= (row>>1)&3 (pre-swizzled global src +
// same-involution ds_read; 16 lanes -> 8 distinct 4-bank groups = conflict-
// free). Two phases/step: {ds_read, stage-issue, barrier, 16 MFMA} (T3),
// setprio(1) around MFMA clusters (T5).
__global__ __launch_bounds__(512, 2) void gemm256(const __bf16* __restrict__ A,
                                                  const __bf16* __restrict__ Bt,
                                                  const float* __restrict__ bias,
                                                  void* __restrict__ Cout,
                                                  int M, int N, int K, int out_bf16) {
  extern __shared__ char smem[];  // 4 * 32768 = 131072 bytes
  const int tid = threadIdx.x;
  const int wid = tid >> 6, lane = tid & 63;
  const int lr = lane & 15, hi = lane >> 4;
  const int wm = wid >> 2, wn = wid & 3;
  const int nbn = N >> 8;
  const int bm = blockIdx.x / nbn, bn = blockIdx.x % nbn;
  const int m0 = bm << 8, n0 = bn << 8;

  // staging coords: thread covers (row0, cg) and (row0+128, cg) of the
  // 256-row x 32-col (4x16B slots) tile; source col pre-swizzled.
  const int row0 = tid >> 2, cg = tid & 3;
  const int cgs = cg ^ ((row0 >> 1) & 3);  // same for row0+128 (bit7 doesn't hit bits1-2)
  const __bf16* pA0 = A + (size_t)(m0 + row0) * K + cgs * 8;
  const __bf16* pA1 = A + (size_t)(m0 + 128 + row0) * K + cgs * 8;
  const __bf16* pB0 = Bt + (size_t)(n0 + row0) * K + cgs * 8;
  const __bf16* pB1 = Bt + (size_t)(n0 + 128 + row0) * K + cgs * 8;

  auto stageA = [&](int ts) {
    char* d = smem + ((ts & 3) << 15) + (wid << 10);
    gload_lds16(pA0 + (size_t)ts * 32, d);
    gload_lds16(pA1 + (size_t)ts * 32, d + 8192);
  };
  auto stageB = [&](int ts) {
    char* d = smem + ((ts & 3) << 15) + 16384 + (wid << 10);
    gload_lds16(pB0 + (size_t)ts * 32, d);
    gload_lds16(pB1 + (size_t)ts * 32, d + 8192);
  };

  // per-thread fragment read offsets (constant across steps)
  int aoff[8], boff[4];
#pragma unroll
  for (int fr = 0; fr < 8; fr++) {
    int ra = wm * 128 + fr * 16 + lr;
    aoff[fr] = ra * 64 + ((hi ^ ((ra >> 1) & 3)) << 4);
  }
#pragma unroll
  for (int fc = 0; fc < 4; fc++) {
    int rb = wn * 64 + fc * 16 + lr;
    boff[fc] = rb * 64 + ((hi ^ ((rb >> 1) & 3)) << 4);
  }

  const f32x4 fz = {0.f, 0.f, 0.f, 0.f};
  f32x4 acc[8][4];
#pragma unroll
  for (int i = 0; i < 8; i++)
#pragma unroll
    for (int j = 0; j < 4; j++) acc[i][j] = fz;

  const int nsteps = K >> 5;  // K/32, >= 4

  auto STEP = [&](int t, bool do_stage) {
    const char* Apt = smem + ((t & 3) << 15);
    const char* Bpt = Apt + 16384;
    bf16x8 bfrag[4], afr[4];
    // ---- phase 0: quadrant rows 0..63 (this wave), all 4 col-frags
    if (do_stage) stageA(t + 3);
#pragma unroll
    for (int fc = 0; fc < 4; fc++) bfrag[fc] = *(const bf16x8*)(Bpt + boff[fc]);
#pragma unroll
    for (int fr = 0; fr < 4; fr++) afr[fr] = *(const bf16x8*)(Apt + aoff[fr]);
    BAR();
    __builtin_amdgcn_s_setprio(1);
#pragma unroll
    for (int fr = 0; fr < 4; fr++)
#pragma unroll
      for (int fc = 0; fc < 4; fc++)
        acc[fr][fc] = mfma_bf16(afr[fr], bfrag[fc], acc[fr][fc]);
    __builtin_amdgcn_s_setprio(0);
    BAR();
    // ---- phase 1: quadrant rows 64..127
    if (do_stage) stageB(t + 3);
#pragma unroll
    for (int fr = 0; fr < 4; fr++) afr[fr] = *(const bf16x8*)(Apt + aoff[4 + fr]);
    BAR();
    __builtin_amdgcn_s_setprio(1);
#pragma unroll
    for (int fr = 0; fr < 4; fr++)
#pragma unroll
      for (int fc = 0; fc < 4; fc++)
        acc[4 + fr][fc] = mfma_bf16(afr[fr], bfrag[fc], acc[4 + fr][fc]);
    __builtin_amdgcn_s_setprio(0);
  };

  // prologue: stage steps 0,1,2 (12 loads/wave in flight)
  stageA(0); stageB(0);
  stageA(1); stageB(1);
  stageA(2); stageB(2);

  int t = 0;
  for (; t < nsteps - 3; ++t) {
    VM8();  // retire step t's 4 loads (t+1,t+2,t+3 stay in flight)
    BAR();
    STEP(t, true);
  }
  VM8(); BAR(); STEP(t, false); ++t;  // outstanding: t,t+1,t+2 -> drain to 8
  VM4(); BAR(); STEP(t, false); ++t;  // outstanding: t,t+1 -> drain to 4
  VM0(); BAR(); STEP(t, false);       // outstanding: t -> drain fully

  // epilogue
  float bv[4];
#pragma unroll
  for (int fc = 0; fc < 4; fc++)
    bv[fc] = bias ? bias[n0 + wn * 64 + fc * 16 + lr] : 0.f;
#pragma unroll
  for (int fr = 0; fr < 8; fr++) {
    int row_base = m0 + wm * 128 + fr * 16 + hi * 4;
#pragma unroll
    for (int fc = 0; fc < 4; fc++) {
      int col = n0 + wn * 64 + fc * 16 + lr;
#pragma unroll
      for (int r = 0; r < 4; r++) {
        int row = row_base + r;
        float v = acc[fr][fc][r] + bv[fc];
        if (out_bf16)
          ((__bf16*)Cout)[(size_t)row * N + col] = (__bf16)v;
        else
          ((float*)Cout)[(size_t)row * N + col] = v;
      }
    }
  }
}

// ---------------- RoPE for q and k ----------------
__global__ __launch_bounds__(256) void rope_qk(const __bf16* __restrict__ qkv,
                                               const int* __restrict__ pos,
                                               __bf16* __restrict__ Qo,
                                               __bf16* __restrict__ Ko) {
  int bs = blockIdx.x;
  int b = bs / Ss, s = bs % Ss;
  float p = (float)pos[s];
  const __bf16* src = qkv + (size_t)bs * QKV_N;
  for (int t = threadIdx.x; t < (NH + NKV) * 64; t += 256) {
    int head = t >> 6, i = t & 63;
    // inv_freq = 10000^(-i/64) = 2^(-i*log2(10000)/64)
    float inv = exp2f((float)i * (-13.287712379549449f / 64.f));
    float sn, cs;
    sincosf(p * inv, &sn, &cs);
    if (head < NH) {
      float x1 = (float)src[head * HD + i];
      float x2 = (float)src[head * HD + i + 64];
      __bf16* dst = Qo + ((size_t)(b * NH + head) * Ss + s) * HD;
      dst[i] = (__bf16)(x1 * cs - x2 * sn);
      dst[i + 64] = (__bf16)(x2 * cs + x1 * sn);
    } else {
      int kh = head - NH;
      float x1 = (float)src[QSZ + kh * HD + i];
      float x2 = (float)src[QSZ + kh * HD + i + 64];
      __bf16* dst = Ko + ((size_t)(b * NKV + kh) * Ss + s) * HD;
      dst[i] = (__bf16)(x1 * cs - x2 * sn);
      dst[i + 64] = (__bf16)(x2 * cs + x1 * sn);
    }
  }
}

// ---------------- V transpose: qkv v-part -> Vt[B][KVH][D][S] ----------------
__global__ __launch_bounds__(256) void vtrans(const __bf16* __restrict__ qkv,
                                              __bf16* __restrict__ Vt) {
  __shared__ __bf16 tile[128][65];
  int bid = blockIdx.x;
  int st_ = bid & 31;
  int kvh = (bid >> 5) & 7;
  int b = bid >> 8;
  int s0 = st_ * 64;
  const __bf16* src = qkv + (size_t)(b * Ss) * QKV_N + (QSZ + KVSZ) + kvh * HD;
  for (int i = threadIdx.x; i < 64 * 128; i += 256) {
    int sl = i >> 7, d = i & 127;
    tile[d][sl] = src[(size_t)(s0 + sl) * QKV_N + d];
  }
  __syncthreads();
  __bf16* dst = Vt + (size_t)(b * NKV + kvh) * HD * Ss;
  for (int i = threadIdx.x; i < 64 * 128; i += 256) {
    int dl = i >> 6, sl = i & 63;
    dst[(size_t)dl * Ss + s0 + sl] = tile[dl][sl];
  }
}

// ---------------- causal flash attention (v3) ----------------
__global__ __launch_bounds__(256) void attn_fwd(const __bf16* __restrict__ Q,
                                                const __bf16* __restrict__ Kk,
                                                const __bf16* __restrict__ Vt,
                                                __bf16* __restrict__ Oa) {
  __shared__ __bf16 Kl[2][64 * 128];   // [64 keys][128 d], 16B slots ^= (row&15)
  __shared__ __bf16 Vl[2][128 * 64];   // [128 d][64 keys], 16B slots ^= (row&7)
  __shared__ __bf16 Pl[4][16 * 64];    // per-wave [16 q][64 keys], slots ^= (row&7)
  const int tid = threadIdx.x, wave = tid >> 6, lane = tid & 63;
  const int nqb = Ss / 64;
  const int bid = blockIdx.x;
  const int b = bid / (NH * nqb);
  const int h = (bid / nqb) % NH;
  const int qb = (nqb - 1) - (bid % nqb);  // heavy blocks early in dispatch
  const int q0 = qb * 64;
  const int kvh = h >> 2;
  const int lr = lane & 15, hi = lane >> 4;
  const f32x4 fz = {0.f, 0.f, 0.f, 0.f};

  const __bf16* qbase = Q + ((size_t)(b * NH + h) * Ss + q0 + wave * 16 + lr) * HD;
  bf16x8 qf[4];
#pragma unroll
  for (int dc = 0; dc < 4; dc++) qf[dc] = *(const bf16x8*)(qbase + dc * 32 + hi * 8);

  f32x4 oacc[8];
#pragma unroll
  for (int i = 0; i < 8; i++) oacc[i] = fz;
  float m_ = -1e30f, l_ = 0.f;

  const __bf16* kbase = Kk + (size_t)(b * NKV + kvh) * Ss * HD;
  const __bf16* vbase = Vt + (size_t)(b * NKV + kvh) * HD * Ss;

  const int nc = qb + 1;  // chunks of 64 keys

  auto STAGE = [&](int c, int buf) {
    const int k0 = c * 64;
#pragma unroll
    for (int i = 0; i < 8; i++) {
      int cidx = wave * 8 + i;
      if (cidx < 16) {
        int r = cidx * 4 + (lane >> 4);  // key row 0..63
        gload_lds16(kbase + (size_t)(k0 + r) * HD + (((lane & 15) ^ (r & 15)) << 3),
                    (char*)Kl[buf] + cidx * 1024);
      } else {
        int cc = cidx - 16;
        int r = cc * 8 + (lane >> 3);    // d row 0..127
        gload_lds16(vbase + (size_t)r * Ss + k0 + (((lane & 7) ^ (r & 7)) << 3),
                    (char*)Vl[buf] + cc * 1024);
      }
    }
  };

  STAGE(0, 0);
  __syncthreads();
  int cur = 0;
  char* pw = (char*)Pl[wave];

  for (int c = 0; c < nc; ++c) {
    if (c + 1 < nc) STAGE(c + 1, cur ^ 1);  // prefetch lands during compute

    const char* Kb = (const char*)Kl[cur];
    const char* Vb = (const char*)Vl[cur];

    // S^T = K Q^T : lane (lr,hi) gets keys 16t+4hi+r of q-row lr
    f32x4 st[4];
#pragma unroll
    for (int t = 0; t < 4; t++) {
      st[t] = fz;
#pragma unroll
      for (int dc = 0; dc < 4; dc++) {
        const bf16x8 kf = *(const bf16x8*)(Kb + (t * 16 + lr) * 256 +
                                           (((dc * 4 + hi) ^ lr) << 4));
        st[t] = mfma_bf16(kf, qf[dc], st[t]);
      }
    }

    const bool diag = (c == nc - 1);
    float s[4][4];
    float mx = -1e30f;
#pragma unroll
    for (int t = 0; t < 4; t++)
#pragma unroll
      for (int r = 0; r < 4; r++) {
        float v = st[t][r] * SCALE;
        if (diag && (t * 16 + hi * 4 + r > wave * 16 + lr)) v = -1e30f;
        s[t][r] = v;
        mx = fmaxf(mx, v);
      }
    mx = fmaxf(mx, __shfl_xor(mx, 16, 64));
    mx = fmaxf(mx, __shfl_xor(mx, 32, 64));

    // defer-max (T13): O-rescale only when running max grows by > 8
    if (__any(mx > m_ + 8.f)) {
      float mn = fmaxf(m_, mx);
      float al = __expf(m_ - mn);
      l_ *= al;
      m_ = mn;
      float alr[4];
#pragma unroll
      for (int r = 0; r < 4; r++) alr[r] = __shfl(al, hi * 4 + r, 64);
#pragma unroll
      for (int dt = 0; dt < 8; dt++)
#pragma unroll
        for (int r = 0; r < 4; r++) oacc[dt][r] *= alr[r];
    }

    float rs = 0.f;
#pragma unroll
    for (int t = 0; t < 4; t++) {
      float p0 = __expf(s[t][0] - m_), p1 = __expf(s[t][1] - m_);
      float p2 = __expf(s[t][2] - m_), p3 = __expf(s[t][3] - m_);
      rs += (p0 + p1) + (p2 + p3);
      bf16x4 pv = {(__bf16)p0, (__bf16)p1, (__bf16)p2, (__bf16)p3};
      // keys 16t+4hi+0..3 of row lr: slot16=(2t+(hi>>1))^(lr&7), half=(hi&1)*8
      *(bf16x4*)(pw + lr * 128 + (((2 * t + (hi >> 1)) ^ (lr & 7)) << 4) +
                 (hi & 1) * 8) = pv;
    }
    rs += __shfl_xor(rs, 16, 64);
    rs += __shfl_xor(rs, 32, 64);
    l_ += rs;

    // PV: pf = P[q=lr][keys 32kf+8hi..], vf = Vt[d=dt*16+lr][keys ...]
    bf16x8 pf[2];
#pragma unroll
    for (int kf_ = 0; kf_ < 2; kf_++)
      pf[kf_] = *(const bf16x8*)(pw + lr * 128 + (((4 * kf_ + hi) ^ (lr & 7)) << 4));
#pragma unroll
    for (int dt = 0; dt < 8; dt++) {
#pragma unroll
      for (int kf_ = 0; kf_ < 2; kf_++) {
        const bf16x8 vf = *(const bf16x8*)(Vb + (dt * 16 + lr) * 128 +
                                           (((kf_ * 4 + hi) ^ (lr & 7)) << 4));
        oacc[dt] = mfma_bf16(pf[kf_], vf, oacc[dt]);
      }
    }

    __syncthreads();  // drains prefetch vmcnt AFTER compute; guards buffer swap
    cur ^= 1;
  }

  float rl[4];
#pragma unroll
  for (int r = 0; r < 4; r++) rl[r] = __shfl(l_, hi * 4 + r, 64);
#pragma unroll
  for (int dt = 0; dt < 8; dt++) {
#pragma unroll
    for (int r = 0; r < 4; r++) {
      int row = q0 + wave * 16 + hi * 4 + r;
      Oa[((size_t)(b * Ss) + row) * QSZ + h * HD + dt * 16 + lr] =
          (__bf16)(oacc[dt][r] / rl[r]);
    }
  }
}

extern "C" void kernel_launch(void* const* d_in, const int* in_sizes, int n_in,
                              void* d_out, int out_size, void* d_ws, size_t ws_size,
                              hipStream_t stream) {
  const int* positions = (const int*)d_in[0];
  const float* hidden = (const float*)d_in[1];
  const float* w_qkv = (const float*)d_in[2];
  const float* b_qkv = (const float*)d_in[3];
  const float* w_o = (const float*)d_in[4];
  float* out = (float*)d_out;

  char* ws = (char*)d_ws;
  // layout (bytes): hs 33.5MB | wqkvT 50.3MB | woT 33.5MB | qkv 50.3MB |
  //                 q 33.5MB | k 8.4MB | vt 8.4MB        total ~218MB
  __bf16* hs = (__bf16*)(ws);
  __bf16* wqkvT = (__bf16*)(ws + 33554432);
  __bf16* woT = (__bf16*)(ws + 83886080);
  __bf16* qkv = (__bf16*)(ws + 117440512);
  __bf16* q = (__bf16*)(ws + 167772160);
  __bf16* k = (__bf16*)(ws + 201326592);
  __bf16* vt = (__bf16*)(ws + 209715200);
  __bf16* attn = hs;  // hs dead after gemm1; reuse for attention output

  f2b<<<2048, 256, 0, stream>>>(hidden, hs, (long)MTOT * HIDDEN / 4);
  transpose_conv<<<(HIDDEN / 64) * (QKV_N / 64), 256, 0, stream>>>(w_qkv, wqkvT, HIDDEN, QKV_N);
  transpose_conv<<<(QSZ / 64) * (HIDDEN / 64), 256, 0, stream>>>(w_o, woT, QSZ, HIDDEN);
  gemm256<<<(MTOT / 256) * (QKV_N / 256), 512, 131072, stream>>>(hs, wqkvT, b_qkv, qkv,
                                                                 MTOT, QKV_N, HIDDEN, 1);
  rope_qk<<<Bb * Ss, 256, 0, stream>>>(qkv, positions, q, k);
  vtrans<<<Bb * NKV * (Ss / 64), 256, 0, stream>>>(qkv, vt);
  attn_fwd<<<Bb * NH * (Ss / 64), 256, 0, stream>>>(q, k, vt, attn);
  gemm256<<<(MTOT / 256) * (QSZ / 256), 512, 131072, stream>>>(attn, woT, nullptr, out,
                                                               MTOT, QSZ, QSZ, 0);
}

// Round 6
// 615.929 us; speedup vs baseline: 1.7604x; 1.0897x over previous
//
#include <hip/hip_runtime.h>
#include <hip/hip_bf16.h>
#include <math.h>

#define HIDDEN 4096
#define NH 32
#define NKV 8
#define HD 128
#define QSZ 4096
#define KVSZ 1024
#define QKV_N 6144
#define Bb 2
#define Ss 2048
#define MTOT 4096   // B*S
#define SCALE 0.08838834764831845f
#define SC2 0.12751743299026142f  // SCALE * log2(e)

typedef __attribute__((ext_vector_type(8))) __bf16 bf16x8;
typedef __attribute__((ext_vector_type(4))) __bf16 bf16x4;
typedef __attribute__((ext_vector_type(4))) float f32x4;

__device__ __forceinline__ f32x4 mfma_bf16(bf16x8 a, bf16x8 b, f32x4 c) {
  return __builtin_amdgcn_mfma_f32_16x16x32_bf16(a, b, c, 0, 0, 0);
}

// global -> LDS direct copy, 16B per lane. LDS dest is wave-uniform base;
// lane l lands at dst + l*16. Global src is per-lane.
__device__ __forceinline__ void gload_lds16(const void* g, void* l) {
  __builtin_amdgcn_global_load_lds((const __attribute__((address_space(1))) void*)g,
                                   (__attribute__((address_space(3))) void*)l, 16, 0, 0);
}

#define VM8() asm volatile("s_waitcnt vmcnt(8)" ::: "memory")
#define VM4() asm volatile("s_waitcnt vmcnt(4)" ::: "memory")
#define VM0() asm volatile("s_waitcnt vmcnt(0)" ::: "memory")
#define BAR() asm volatile("s_barrier" ::: "memory")

// ---------------- elementwise f32 -> bf16 (vectorized) ----------------
__global__ __launch_bounds__(256) void f2b(const float* __restrict__ in,
                                           __bf16* __restrict__ out, long n4) {
  for (long i = (long)blockIdx.x * blockDim.x + threadIdx.x; i < n4;
       i += (long)gridDim.x * blockDim.x) {
    float4 v = ((const float4*)in)[i];
    bf16x4 o = {(__bf16)v.x, (__bf16)v.y, (__bf16)v.z, (__bf16)v.w};
    ((bf16x4*)out)[i] = o;
  }
}

// ---------------- transpose + convert: w[K][N] f32 -> wT[N][K] bf16 ----------------
__global__ __launch_bounds__(256) void transpose_conv(const float* __restrict__ w,
                                                      __bf16* __restrict__ wT,
                                                      int K, int N) {
  __shared__ __bf16 tile[64][65];
  int nb = N >> 6;
  int kt = blockIdx.x / nb, nt = blockIdx.x % nb;
  for (int i = threadIdx.x; i < 64 * 64; i += 256) {
    int kl = i >> 6, nl = i & 63;
    tile[kl][nl] = (__bf16)w[(size_t)(kt * 64 + kl) * N + (nt * 64 + nl)];
  }
  __syncthreads();
  for (int i = threadIdx.x; i < 64 * 64; i += 256) {
    int nl = i >> 6, kl = i & 63;
    wT[(size_t)(nt * 64 + nl) * K + (kt * 64 + kl)] = tile[kl][nl];
  }
}

// ---------------- GEMM 256x256 deep-pipelined: C[M][N] = A * Bt^T (+bias) ----------
// 8 waves (2M x 4N), per-wave 128x64 output. BK=32. Ring of 4 LDS buffers,
// staged 3 K-steps ahead via global_load_lds. Counted vmcnt(8) + raw barrier
// (T4). 16B-slot swizzle slot^=(row>>1)&3 (T2, rule 21). setprio around MFMA
// clusters (T5).
__global__ __launch_bounds__(512, 2) void gemm256(const __bf16* __restrict__ A,
                                                  const __bf16* __restrict__ Bt,
                                                  const float* __restrict__ bias,
                                                  void* __restrict__ Cout,
                                                  int M, int N, int K, int out_bf16) {
  extern __shared__ char smem[];  // 4 * 32768 = 131072 bytes
  const int tid = threadIdx.x;
  const int wid = tid >> 6, lane = tid & 63;
  const int lr = lane & 15, hi = lane >> 4;
  const int wm = wid >> 2, wn = wid & 3;
  const int nbn = N >> 8;
  const int bm = blockIdx.x / nbn, bn = blockIdx.x % nbn;
  const int m0 = bm << 8, n0 = bn << 8;

  const int row0 = tid >> 2, cg = tid & 3;
  const int cgs = cg ^ ((row0 >> 1) & 3);
  const __bf16* pA0 = A + (size_t)(m0 + row0) * K + cgs * 8;
  const __bf16* pA1 = A + (size_t)(m0 + 128 + row0) * K + cgs * 8;
  const __bf16* pB0 = Bt + (size_t)(n0 + row0) * K + cgs * 8;
  const __bf16* pB1 = Bt + (size_t)(n0 + 128 + row0) * K + cgs * 8;

  auto stageA = [&](int ts) {
    char* d = smem + ((ts & 3) << 15) + (wid << 10);
    gload_lds16(pA0 + (size_t)ts * 32, d);
    gload_lds16(pA1 + (size_t)ts * 32, d + 8192);
  };
  auto stageB = [&](int ts) {
    char* d = smem + ((ts & 3) << 15) + 16384 + (wid << 10);
    gload_lds16(pB0 + (size_t)ts * 32, d);
    gload_lds16(pB1 + (size_t)ts * 32, d + 8192);
  };

  int aoff[8], boff[4];
#pragma unroll
  for (int fr = 0; fr < 8; fr++) {
    int ra = wm * 128 + fr * 16 + lr;
    aoff[fr] = ra * 64 + ((hi ^ ((ra >> 1) & 3)) << 4);
  }
#pragma unroll
  for (int fc = 0; fc < 4; fc++) {
    int rb = wn * 64 + fc * 16 + lr;
    boff[fc] = rb * 64 + ((hi ^ ((rb >> 1) & 3)) << 4);
  }

  const f32x4 fz = {0.f, 0.f, 0.f, 0.f};
  f32x4 acc[8][4];
#pragma unroll
  for (int i = 0; i < 8; i++)
#pragma unroll
    for (int j = 0; j < 4; j++) acc[i][j] = fz;

  const int nsteps = K >> 5;  // K/32, >= 4

  auto STEP = [&](int t, bool do_stage) {
    const char* Apt = smem + ((t & 3) << 15);
    const char* Bpt = Apt + 16384;
    bf16x8 bfrag[4], afr[4];
    if (do_stage) stageA(t + 3);
#pragma unroll
    for (int fc = 0; fc < 4; fc++) bfrag[fc] = *(const bf16x8*)(Bpt + boff[fc]);
#pragma unroll
    for (int fr = 0; fr < 4; fr++) afr[fr] = *(const bf16x8*)(Apt + aoff[fr]);
    BAR();
    __builtin_amdgcn_s_setprio(1);
#pragma unroll
    for (int fr = 0; fr < 4; fr++)
#pragma unroll
      for (int fc = 0; fc < 4; fc++)
        acc[fr][fc] = mfma_bf16(afr[fr], bfrag[fc], acc[fr][fc]);
    __builtin_amdgcn_s_setprio(0);
    BAR();
    if (do_stage) stageB(t + 3);
#pragma unroll
    for (int fr = 0; fr < 4; fr++) afr[fr] = *(const bf16x8*)(Apt + aoff[4 + fr]);
    BAR();
    __builtin_amdgcn_s_setprio(1);
#pragma unroll
    for (int fr = 0; fr < 4; fr++)
#pragma unroll
      for (int fc = 0; fc < 4; fc++)
        acc[4 + fr][fc] = mfma_bf16(afr[fr], bfrag[fc], acc[4 + fr][fc]);
    __builtin_amdgcn_s_setprio(0);
  };

  stageA(0); stageB(0);
  stageA(1); stageB(1);
  stageA(2); stageB(2);

  int t = 0;
  for (; t < nsteps - 3; ++t) {
    VM8();
    BAR();
    STEP(t, true);
  }
  VM8(); BAR(); STEP(t, false); ++t;
  VM4(); BAR(); STEP(t, false); ++t;
  VM0(); BAR(); STEP(t, false);

  float bv[4];
#pragma unroll
  for (int fc = 0; fc < 4; fc++)
    bv[fc] = bias ? bias[n0 + wn * 64 + fc * 16 + lr] : 0.f;
#pragma unroll
  for (int fr = 0; fr < 8; fr++) {
    int row_base = m0 + wm * 128 + fr * 16 + hi * 4;
#pragma unroll
    for (int fc = 0; fc < 4; fc++) {
      int col = n0 + wn * 64 + fc * 16 + lr;
#pragma unroll
      for (int r = 0; r < 4; r++) {
        int row = row_base + r;
        float v = acc[fr][fc][r] + bv[fc];
        if (out_bf16)
          ((__bf16*)Cout)[(size_t)row * N + col] = (__bf16)v;
        else
          ((float*)Cout)[(size_t)row * N + col] = v;
      }
    }
  }
}

// ---------------- RoPE for q and k ----------------
__global__ __launch_bounds__(256) void rope_qk(const __bf16* __restrict__ qkv,
                                               const int* __restrict__ pos,
                                               __bf16* __restrict__ Qo,
                                               __bf16* __restrict__ Ko) {
  int bs = blockIdx.x;
  int b = bs / Ss, s = bs % Ss;
  float p = (float)pos[s];
  const __bf16* src = qkv + (size_t)bs * QKV_N;
  for (int t = threadIdx.x; t < (NH + NKV) * 64; t += 256) {
    int head = t >> 6, i = t & 63;
    float inv = exp2f((float)i * (-13.287712379549449f / 64.f));
    float sn, cs;
    sincosf(p * inv, &sn, &cs);
    if (head < NH) {
      float x1 = (float)src[head * HD + i];
      float x2 = (float)src[head * HD + i + 64];
      __bf16* dst = Qo + ((size_t)(b * NH + head) * Ss + s) * HD;
      dst[i] = (__bf16)(x1 * cs - x2 * sn);
      dst[i + 64] = (__bf16)(x2 * cs + x1 * sn);
    } else {
      int kh = head - NH;
      float x1 = (float)src[QSZ + kh * HD + i];
      float x2 = (float)src[QSZ + kh * HD + i + 64];
      __bf16* dst = Ko + ((size_t)(b * NKV + kh) * Ss + s) * HD;
      dst[i] = (__bf16)(x1 * cs - x2 * sn);
      dst[i + 64] = (__bf16)(x2 * cs + x1 * sn);
    }
  }
}

// ---------------- V transpose: qkv v-part -> Vt[B][KVH][D][S] ----------------
__global__ __launch_bounds__(256) void vtrans(const __bf16* __restrict__ qkv,
                                              __bf16* __restrict__ Vt) {
  __shared__ __bf16 tile[128][65];
  int bid = blockIdx.x;
  int st_ = bid & 31;
  int kvh = (bid >> 5) & 7;
  int b = bid >> 8;
  int s0 = st_ * 64;
  const __bf16* src = qkv + (size_t)(b * Ss) * QKV_N + (QSZ + KVSZ) + kvh * HD;
  for (int i = threadIdx.x; i < 64 * 128; i += 256) {
    int sl = i >> 7, d = i & 127;
    tile[d][sl] = src[(size_t)(s0 + sl) * QKV_N + d];
  }
  __syncthreads();
  __bf16* dst = Vt + (size_t)(b * NKV + kvh) * HD * Ss;
  for (int i = threadIdx.x; i < 64 * 128; i += 256) {
    int dl = i >> 6, sl = i & 63;
    dst[(size_t)dl * Ss + s0 + sl] = tile[dl][sl];
  }
}

// ---------------- causal flash attention (v4) ----------------
// grid: B*NH*(S/128); block 512 = 8 waves, each wave owns 16 q rows
// (QBLK=128). KVBLK=64, double-buffered K/V; waves 0-3 stage K, waves 4-7
// stage V with hoisted per-lane source pointers (chunk-invariant swizzled
// offsets + running base). Swapped QK^T softmax in exp2 domain; defer-max
// (T13, thr=8 log2); per-wave uniform skip of fully-masked chunks.
// LDS 80KB -> 2 blocks/CU = 16 waves/CU (4/SIMD).
__global__ __launch_bounds__(512, 4) void attn_fwd(const __bf16* __restrict__ Q,
                                                   const __bf16* __restrict__ Kk,
                                                   const __bf16* __restrict__ Vt,
                                                   __bf16* __restrict__ Oa) {
  __shared__ __bf16 Kl[2][64 * 128];   // [64 keys][128 d], 16B slots ^= (row&15)
  __shared__ __bf16 Vl[2][128 * 64];   // [128 d][64 keys], 16B slots ^= (row&7)
  __shared__ __bf16 Pl[8][16 * 64];    // per-wave [16 q][64 keys], slots ^= (row&7)
  const int tid = threadIdx.x, wave = tid >> 6, lane = tid & 63;
  const int nqb = Ss / 128;            // 16
  const int bid = blockIdx.x;
  const int b = bid / (NH * nqb);
  const int h = (bid / nqb) % NH;
  const int qb = (nqb - 1) - (bid % nqb);  // heavy blocks early in dispatch
  const int q0 = qb * 128;
  const int kvh = h >> 2;
  const int lr = lane & 15, hi = lane >> 4;
  const f32x4 fz = {0.f, 0.f, 0.f, 0.f};

  const __bf16* qbase = Q + ((size_t)(b * NH + h) * Ss + q0 + wave * 16 + lr) * HD;
  bf16x8 qf[4];
#pragma unroll
  for (int dc = 0; dc < 4; dc++) qf[dc] = *(const bf16x8*)(qbase + dc * 32 + hi * 8);

  f32x4 oacc[8];
#pragma unroll
  for (int i = 0; i < 8; i++) oacc[i] = fz;
  float m_ = -1e30f, l_ = 0.f;

  const __bf16* kbase = Kk + (size_t)(b * NKV + kvh) * Ss * HD;
  const __bf16* vbase = Vt + (size_t)(b * NKV + kvh) * HD * Ss;

  // hoisted staging: waves 0-3 stage K chunks wave*4+i; waves 4-7 V chunks.
  // per-lane swizzled offsets are chunk-invariant; base advances per chunk.
  const __bf16* srun;
  int soff[4], sldso[4], sstep;
  char* ldsbase;
  if (wave < 4) {
#pragma unroll
    for (int i = 0; i < 4; i++) {
      int cidx = wave * 4 + i;
      int r = cidx * 4 + (lane >> 4);  // key row 0..63
      soff[i] = r * HD + (((lane & 15) ^ (r & 15)) << 3);
      sldso[i] = cidx << 10;
    }
    srun = kbase;
    sstep = 64 * HD;
    ldsbase = (char*)Kl;
  } else {
#pragma unroll
    for (int i = 0; i < 4; i++) {
      int cc = (wave - 4) * 4 + i;
      int r = cc * 8 + (lane >> 3);    // d row 0..127
      soff[i] = r * Ss + (((lane & 7) ^ (r & 7)) << 3);
      sldso[i] = cc << 10;
    }
    srun = vbase;
    sstep = 64;
    ldsbase = (char*)Vl;
  }

  auto STAGE = [&](int buf) {
    char* dbase = ldsbase + (buf << 14);
#pragma unroll
    for (int i = 0; i < 4; i++) gload_lds16(srun + soff[i], dbase + sldso[i]);
    srun += sstep;
  };

  STAGE(0);
  __syncthreads();
  int cur = 0;
  char* pw = (char*)Pl[wave];
  const int nc = 2 * qb + 2;           // chunks of 64 keys
  const int wrow0 = q0 + wave * 16;    // this wave's first q row

  for (int c = 0; c < nc; ++c) {
    if (c + 1 < nc) STAGE(cur ^ 1);    // prefetch lands during compute
    const int k0 = c * 64;
    const bool active = (k0 <= wrow0 + 15);  // wave-uniform

    if (active) {
      const char* Kb = (const char*)Kl[cur];
      const char* Vb = (const char*)Vl[cur];

      // S^T = K Q^T : lane (lr,hi) gets keys 16t+4hi+r of q-row lr
      f32x4 st[4];
#pragma unroll
      for (int t = 0; t < 4; t++) {
        st[t] = fz;
#pragma unroll
        for (int dc = 0; dc < 4; dc++) {
          const bf16x8 kf = *(const bf16x8*)(Kb + (t * 16 + lr) * 256 +
                                             (((dc * 4 + hi) ^ lr) << 4));
          st[t] = mfma_bf16(kf, qf[dc], st[t]);
        }
      }

      const bool needMask = (k0 + 63 > wrow0);  // wave-uniform
      const int rel = wrow0 + lr - k0;
      float s2[4][4];
      float mx = -1e30f;
#pragma unroll
      for (int t = 0; t < 4; t++)
#pragma unroll
        for (int r = 0; r < 4; r++) {
          float v = st[t][r] * SC2;  // log2 domain
          if (needMask && (16 * t + 4 * hi + r > rel)) v = -1e30f;
          s2[t][r] = v;
          mx = fmaxf(mx, v);
        }
      mx = fmaxf(mx, __shfl_xor(mx, 16, 64));
      mx = fmaxf(mx, __shfl_xor(mx, 32, 64));

      // defer-max (T13): O-rescale only when running max grows by > 8 (log2)
      if (__any(mx > m_ + 8.f)) {
        float mn = fmaxf(m_, mx);
        float al = exp2f(m_ - mn);
        l_ *= al;
        m_ = mn;
        float alr[4];
#pragma unroll
        for (int r = 0; r < 4; r++) alr[r] = __shfl(al, hi * 4 + r, 64);
#pragma unroll
        for (int dt = 0; dt < 8; dt++)
#pragma unroll
          for (int r = 0; r < 4; r++) oacc[dt][r] *= alr[r];
      }

      float rs = 0.f;
#pragma unroll
      for (int t = 0; t < 4; t++) {
        float p0 = exp2f(s2[t][0] - m_), p1 = exp2f(s2[t][1] - m_);
        float p2 = exp2f(s2[t][2] - m_), p3 = exp2f(s2[t][3] - m_);
        rs += (p0 + p1) + (p2 + p3);
        bf16x4 pv = {(__bf16)p0, (__bf16)p1, (__bf16)p2, (__bf16)p3};
        *(bf16x4*)(pw + lr * 128 + (((2 * t + (hi >> 1)) ^ (lr & 7)) << 4) +
                   (hi & 1) * 8) = pv;
      }
      rs += __shfl_xor(rs, 16, 64);
      rs += __shfl_xor(rs, 32, 64);
      l_ += rs;

      // PV: pf = P[q=lr][keys 32kf+8hi..], vf = Vt[d=dt*16+lr][keys ...]
      bf16x8 pf[2];
#pragma unroll
      for (int kf_ = 0; kf_ < 2; kf_++)
        pf[kf_] = *(const bf16x8*)(pw + lr * 128 + (((4 * kf_ + hi) ^ (lr & 7)) << 4));
#pragma unroll
      for (int dt = 0; dt < 8; dt++) {
#pragma unroll
        for (int kf_ = 0; kf_ < 2; kf_++) {
          const bf16x8 vf = *(const bf16x8*)(Vb + (dt * 16 + lr) * 128 +
                                             (((kf_ * 4 + hi) ^ (lr & 7)) << 4));
          oacc[dt] = mfma_bf16(pf[kf_], vf, oacc[dt]);
        }
      }
    }

    __syncthreads();  // drains prefetch vmcnt AFTER compute; guards buffer swap
    cur ^= 1;
  }

  float rl[4];
#pragma unroll
  for (int r = 0; r < 4; r++) rl[r] = __shfl(l_, hi * 4 + r, 64);
#pragma unroll
  for (int dt = 0; dt < 8; dt++) {
#pragma unroll
    for (int r = 0; r < 4; r++) {
      int row = q0 + wave * 16 + hi * 4 + r;
      Oa[((size_t)(b * Ss) + row) * QSZ + h * HD + dt * 16 + lr] =
          (__bf16)(oacc[dt][r] / rl[r]);
    }
  }
}

extern "C" void kernel_launch(void* const* d_in, const int* in_sizes, int n_in,
                              void* d_out, int out_size, void* d_ws, size_t ws_size,
                              hipStream_t stream) {
  const int* positions = (const int*)d_in[0];
  const float* hidden = (const float*)d_in[1];
  const float* w_qkv = (const float*)d_in[2];
  const float* b_qkv = (const float*)d_in[3];
  const float* w_o = (const float*)d_in[4];
  float* out = (float*)d_out;

  char* ws = (char*)d_ws;
  __bf16* hs = (__bf16*)(ws);
  __bf16* wqkvT = (__bf16*)(ws + 33554432);
  __bf16* woT = (__bf16*)(ws + 83886080);
  __bf16* qkv = (__bf16*)(ws + 117440512);
  __bf16* q = (__bf16*)(ws + 167772160);
  __bf16* k = (__bf16*)(ws + 201326592);
  __bf16* vt = (__bf16*)(ws + 209715200);
  __bf16* attn = hs;  // hs dead after gemm1; reuse for attention output

  f2b<<<2048, 256, 0, stream>>>(hidden, hs, (long)MTOT * HIDDEN / 4);
  transpose_conv<<<(HIDDEN / 64) * (QKV_N / 64), 256, 0, stream>>>(w_qkv, wqkvT, HIDDEN, QKV_N);
  transpose_conv<<<(QSZ / 64) * (HIDDEN / 64), 256, 0, stream>>>(w_o, woT, QSZ, HIDDEN);
  gemm256<<<(MTOT / 256) * (QKV_N / 256), 512, 131072, stream>>>(hs, wqkvT, b_qkv, qkv,
                                                                 MTOT, QKV_N, HIDDEN, 1);
  rope_qk<<<Bb * Ss, 256, 0, stream>>>(qkv, positions, q, k);
  vtrans<<<Bb * NKV * (Ss / 64), 256, 0, stream>>>(qkv, vt);
  attn_fwd<<<Bb * NH * (Ss / 128), 512, 0, stream>>>(q, k, vt, attn);
  gemm256<<<(MTOT / 256) * (QSZ / 256), 512, 131072, stream>>>(attn, woT, nullptr, out,
                                                               MTOT, QSZ, QSZ, 0);
}

// Round 7
// 594.682 us; speedup vs baseline: 1.8233x; 1.0357x over previous
//
#include <hip/hip_runtime.h>
#include <hip/hip_bf16.h>
#include <math.h>

#define HIDDEN 4096
#define NH 32
#define NKV 8
#define HD 128
#define QSZ 4096
#define KVSZ 1024
#define QKV_N 6144
#define Bb 2
#define Ss 2048
#define MTOT 4096   // B*S
#define SCALE 0.08838834764831845f
#define SC2 0.12751743299026142f  // SCALE * log2(e)

typedef __attribute__((ext_vector_type(8))) __bf16 bf16x8;
typedef __attribute__((ext_vector_type(4))) __bf16 bf16x4;
typedef __attribute__((ext_vector_type(4))) float f32x4;

__device__ __forceinline__ f32x4 mfma_bf16(bf16x8 a, bf16x8 b, f32x4 c) {
  return __builtin_amdgcn_mfma_f32_16x16x32_bf16(a, b, c, 0, 0, 0);
}

// global -> LDS direct copy, 16B per lane. LDS dest is wave-uniform base;
// lane l lands at dst + l*16. Global src is per-lane.
__device__ __forceinline__ void gload_lds16(const void* g, void* l) {
  __builtin_amdgcn_global_load_lds((const __attribute__((address_space(1))) void*)g,
                                   (__attribute__((address_space(3))) void*)l, 16, 0, 0);
}

#define VM8() asm volatile("s_waitcnt vmcnt(8)" ::: "memory")
#define VM4() asm volatile("s_waitcnt vmcnt(4)" ::: "memory")
#define VM0() asm volatile("s_waitcnt vmcnt(0)" ::: "memory")
#define BAR() asm volatile("s_barrier" ::: "memory")

// ---------------- elementwise f32 -> bf16 (vectorized) ----------------
__global__ __launch_bounds__(256) void f2b(const float* __restrict__ in,
                                           __bf16* __restrict__ out, long n4) {
  for (long i = (long)blockIdx.x * blockDim.x + threadIdx.x; i < n4;
       i += (long)gridDim.x * blockDim.x) {
    float4 v = ((const float4*)in)[i];
    bf16x4 o = {(__bf16)v.x, (__bf16)v.y, (__bf16)v.z, (__bf16)v.w};
    ((bf16x4*)out)[i] = o;
  }
}

// ---------------- transpose + convert: w[K][N] f32 -> wT[N][K] bf16 ----------------
__global__ __launch_bounds__(256) void transpose_conv(const float* __restrict__ w,
                                                      __bf16* __restrict__ wT,
                                                      int K, int N) {
  __shared__ __bf16 tile[64][65];
  int nb = N >> 6;
  int kt = blockIdx.x / nb, nt = blockIdx.x % nb;
  for (int i = threadIdx.x; i < 64 * 64; i += 256) {
    int kl = i >> 6, nl = i & 63;
    tile[kl][nl] = (__bf16)w[(size_t)(kt * 64 + kl) * N + (nt * 64 + nl)];
  }
  __syncthreads();
  for (int i = threadIdx.x; i < 64 * 64; i += 256) {
    int nl = i >> 6, kl = i & 63;
    wT[(size_t)(nt * 64 + nl) * K + (kt * 64 + kl)] = tile[kl][nl];
  }
}

// ---------------- templated deep-pipelined GEMM: C[M][N] = A * Bt^T (+bias) -------
// 8 waves (2M x 4N). Tile BM=32*MF x BN=64*NF, BK=32. Ring of 4 LDS buffers
// (32KB each), staged 3 K-steps ahead via global_load_lds; per-thread 4 loads
// per step for both instantiations. Boundary per K-step: counted
// s_waitcnt vmcnt(8) + ONE raw s_barrier (T4): per-wave FIFO vmcnt retires
// exactly step-t's loads, barrier then proves all waves' loads landed; WAR on
// ring slot t-1 is safe because every ds_read of step t-1 fed an MFMA before
// that wave reached this barrier. 16B-slot swizzle slot^=(row>>1)&3 (T2, rule
// 21: linear LDS dest, pre-swizzled global src, same-involution ds_read).
// setprio(1) around the MFMA cluster (T5). XCD chunked swizzle (T1, grid%8==0).
template <int MF, int NF>
__global__ __launch_bounds__(512, 2) void gemm_t(const __bf16* __restrict__ A,
                                                 const __bf16* __restrict__ Bt,
                                                 const float* __restrict__ bias,
                                                 void* __restrict__ Cout,
                                                 int M, int N, int K, int out_bf16) {
  constexpr int BM = 32 * MF, BN = 64 * NF;
  constexpr int ABYTES = BM * 64;          // BM rows x 32 cols x 2B
  constexpr int BUF = ABYTES + BN * 64;    // 32 KB for both instantiations
  constexpr int NA = MF / 4, NB = NF / 2;
  extern __shared__ char smem[];           // 4 * BUF = 128 KiB
  const int tid = threadIdx.x;
  const int wid = tid >> 6, lane = tid & 63;
  const int lr = lane & 15, hi = lane >> 4;
  const int wm = wid >> 2, wn = wid & 3;
  const int nbn = N / BN;
  const int nwg = gridDim.x;
  const int tile = ((blockIdx.x & 7) * (nwg >> 3)) + (blockIdx.x >> 3);  // T1
  const int bm = tile / nbn, bn = tile % nbn;
  const int m0 = bm * BM, n0 = bn * BN;

  // staging: thread covers rows row0 + i*128, col-group cg (16B) of the
  // [rows][32] bf16 tile; source col pre-swizzled (row bits 7+ don't touch
  // bits 1-2 of the swizzle, so cgs is shared by all i).
  const int row0 = tid >> 2, cg = tid & 3;
  const int cgs = cg ^ ((row0 >> 1) & 3);
  const __bf16* pA[NA];
  const __bf16* pB[NB];
#pragma unroll
  for (int i = 0; i < NA; i++)
    pA[i] = A + (size_t)(m0 + row0 + i * 128) * K + cgs * 8;
#pragma unroll
  for (int j = 0; j < NB; j++)
    pB[j] = Bt + (size_t)(n0 + row0 + j * 128) * K + cgs * 8;

  auto stage = [&](int ts) {
    char* d = smem + (size_t)((ts & 3) * BUF) + (wid << 10);
#pragma unroll
    for (int i = 0; i < NA; i++) gload_lds16(pA[i] + (size_t)ts * 32, d + i * 8192);
#pragma unroll
    for (int j = 0; j < NB; j++)
      gload_lds16(pB[j] + (size_t)ts * 32, d + ABYTES + j * 8192);
  };

  int aoff[MF], boff[NF];
#pragma unroll
  for (int fr = 0; fr < MF; fr++) {
    int ra = wm * (16 * MF) + fr * 16 + lr;
    aoff[fr] = ra * 64 + ((hi ^ ((ra >> 1) & 3)) << 4);
  }
#pragma unroll
  for (int fc = 0; fc < NF; fc++) {
    int rb = wn * (16 * NF) + fc * 16 + lr;
    boff[fc] = ABYTES + rb * 64 + ((hi ^ ((rb >> 1) & 3)) << 4);
  }

  const f32x4 fz = {0.f, 0.f, 0.f, 0.f};
  f32x4 acc[MF][NF];
#pragma unroll
  for (int i = 0; i < MF; i++)
#pragma unroll
    for (int j = 0; j < NF; j++) acc[i][j] = fz;

  const int nsteps = K >> 5;  // K/32, >= 4

  auto STEP = [&](int t, bool do_stage) {
    const char* base = smem + (size_t)((t & 3) * BUF);
    if (do_stage) stage(t + 3);
    bf16x8 bfr[NF], afr[MF];
#pragma unroll
    for (int fc = 0; fc < NF; fc++) bfr[fc] = *(const bf16x8*)(base + boff[fc]);
#pragma unroll
    for (int fr = 0; fr < MF; fr++) afr[fr] = *(const bf16x8*)(base + aoff[fr]);
    __builtin_amdgcn_s_setprio(1);
#pragma unroll
    for (int fr = 0; fr < MF; fr++)
#pragma unroll
      for (int fc = 0; fc < NF; fc++)
        acc[fr][fc] = mfma_bf16(afr[fr], bfr[fc], acc[fr][fc]);
    __builtin_amdgcn_s_setprio(0);
  };

  stage(0);
  stage(1);
  stage(2);

  int t = 0;
  for (; t < nsteps - 3; ++t) {
    VM8();   // retire step t's 4 loads (t+1,t+2,t+3 stay in flight)
    BAR();   // all waves' step-t loads landed; slot t-1 reads all consumed
    STEP(t, true);
  }
  VM8(); BAR(); STEP(t, false); ++t;
  VM4(); BAR(); STEP(t, false); ++t;
  VM0(); BAR(); STEP(t, false);

  // epilogue
  float bv[NF];
#pragma unroll
  for (int fc = 0; fc < NF; fc++)
    bv[fc] = bias ? bias[n0 + wn * (16 * NF) + fc * 16 + lr] : 0.f;
#pragma unroll
  for (int fr = 0; fr < MF; fr++) {
    int row_base = m0 + wm * (16 * MF) + fr * 16 + hi * 4;
#pragma unroll
    for (int fc = 0; fc < NF; fc++) {
      int col = n0 + wn * (16 * NF) + fc * 16 + lr;
#pragma unroll
      for (int r = 0; r < 4; r++) {
        int row = row_base + r;
        float v = acc[fr][fc][r] + bv[fc];
        if (out_bf16)
          ((__bf16*)Cout)[(size_t)row * N + col] = (__bf16)v;
        else
          ((float*)Cout)[(size_t)row * N + col] = v;
      }
    }
  }
}

// ---------------- RoPE for q and k ----------------
__global__ __launch_bounds__(256) void rope_qk(const __bf16* __restrict__ qkv,
                                               const int* __restrict__ pos,
                                               __bf16* __restrict__ Qo,
                                               __bf16* __restrict__ Ko) {
  int bs = blockIdx.x;
  int b = bs / Ss, s = bs % Ss;
  float p = (float)pos[s];
  const __bf16* src = qkv + (size_t)bs * QKV_N;
  for (int t = threadIdx.x; t < (NH + NKV) * 64; t += 256) {
    int head = t >> 6, i = t & 63;
    float inv = exp2f((float)i * (-13.287712379549449f / 64.f));
    float sn, cs;
    sincosf(p * inv, &sn, &cs);
    if (head < NH) {
      float x1 = (float)src[head * HD + i];
      float x2 = (float)src[head * HD + i + 64];
      __bf16* dst = Qo + ((size_t)(b * NH + head) * Ss + s) * HD;
      dst[i] = (__bf16)(x1 * cs - x2 * sn);
      dst[i + 64] = (__bf16)(x2 * cs + x1 * sn);
    } else {
      int kh = head - NH;
      float x1 = (float)src[QSZ + kh * HD + i];
      float x2 = (float)src[QSZ + kh * HD + i + 64];
      __bf16* dst = Ko + ((size_t)(b * NKV + kh) * Ss + s) * HD;
      dst[i] = (__bf16)(x1 * cs - x2 * sn);
      dst[i + 64] = (__bf16)(x2 * cs + x1 * sn);
    }
  }
}

// ---------------- V transpose: qkv v-part -> Vt[B][KVH][D][S] ----------------
__global__ __launch_bounds__(256) void vtrans(const __bf16* __restrict__ qkv,
                                              __bf16* __restrict__ Vt) {
  __shared__ __bf16 tile[128][65];
  int bid = blockIdx.x;
  int st_ = bid & 31;
  int kvh = (bid >> 5) & 7;
  int b = bid >> 8;
  int s0 = st_ * 64;
  const __bf16* src = qkv + (size_t)(b * Ss) * QKV_N + (QSZ + KVSZ) + kvh * HD;
  for (int i = threadIdx.x; i < 64 * 128; i += 256) {
    int sl = i >> 7, d = i & 127;
    tile[d][sl] = src[(size_t)(s0 + sl) * QKV_N + d];
  }
  __syncthreads();
  __bf16* dst = Vt + (size_t)(b * NKV + kvh) * HD * Ss;
  for (int i = threadIdx.x; i < 64 * 128; i += 256) {
    int dl = i >> 6, sl = i & 63;
    dst[(size_t)dl * Ss + s0 + sl] = tile[dl][sl];
  }
}

// ---------------- causal flash attention (v4) ----------------
// grid: B*NH*(S/128); block 512 = 8 waves, each wave owns 16 q rows
// (QBLK=128). KVBLK=64, double-buffered K/V; waves 0-3 stage K, waves 4-7
// stage V with hoisted per-lane source pointers. Swapped QK^T softmax in exp2
// domain; defer-max (T13); per-wave uniform skip of fully-masked chunks.
__global__ __launch_bounds__(512, 4) void attn_fwd(const __bf16* __restrict__ Q,
                                                   const __bf16* __restrict__ Kk,
                                                   const __bf16* __restrict__ Vt,
                                                   __bf16* __restrict__ Oa) {
  __shared__ __bf16 Kl[2][64 * 128];   // [64 keys][128 d], 16B slots ^= (row&15)
  __shared__ __bf16 Vl[2][128 * 64];   // [128 d][64 keys], 16B slots ^= (row&7)
  __shared__ __bf16 Pl[8][16 * 64];    // per-wave [16 q][64 keys], slots ^= (row&7)
  const int tid = threadIdx.x, wave = tid >> 6, lane = tid & 63;
  const int nqb = Ss / 128;            // 16
  const int bid = blockIdx.x;
  const int b = bid / (NH * nqb);
  const int h = (bid / nqb) % NH;
  const int qb = (nqb - 1) - (bid % nqb);  // heavy blocks early in dispatch
  const int q0 = qb * 128;
  const int kvh = h >> 2;
  const int lr = lane & 15, hi = lane >> 4;
  const f32x4 fz = {0.f, 0.f, 0.f, 0.f};

  const __bf16* qbase = Q + ((size_t)(b * NH + h) * Ss + q0 + wave * 16 + lr) * HD;
  bf16x8 qf[4];
#pragma unroll
  for (int dc = 0; dc < 4; dc++) qf[dc] = *(const bf16x8*)(qbase + dc * 32 + hi * 8);

  f32x4 oacc[8];
#pragma unroll
  for (int i = 0; i < 8; i++) oacc[i] = fz;
  float m_ = -1e30f, l_ = 0.f;

  const __bf16* kbase = Kk + (size_t)(b * NKV + kvh) * Ss * HD;
  const __bf16* vbase = Vt + (size_t)(b * NKV + kvh) * HD * Ss;

  const __bf16* srun;
  int soff[4], sldso[4], sstep;
  char* ldsbase;
  if (wave < 4) {
#pragma unroll
    for (int i = 0; i < 4; i++) {
      int cidx = wave * 4 + i;
      int r = cidx * 4 + (lane >> 4);  // key row 0..63
      soff[i] = r * HD + (((lane & 15) ^ (r & 15)) << 3);
      sldso[i] = cidx << 10;
    }
    srun = kbase;
    sstep = 64 * HD;
    ldsbase = (char*)Kl;
  } else {
#pragma unroll
    for (int i = 0; i < 4; i++) {
      int cc = (wave - 4) * 4 + i;
      int r = cc * 8 + (lane >> 3);    // d row 0..127
      soff[i] = r * Ss + (((lane & 7) ^ (r & 7)) << 3);
      sldso[i] = cc << 10;
    }
    srun = vbase;
    sstep = 64;
    ldsbase = (char*)Vl;
  }

  auto STAGE = [&](int buf) {
    char* dbase = ldsbase + (buf << 14);
#pragma unroll
    for (int i = 0; i < 4; i++) gload_lds16(srun + soff[i], dbase + sldso[i]);
    srun += sstep;
  };

  STAGE(0);
  __syncthreads();
  int cur = 0;
  char* pw = (char*)Pl[wave];
  const int nc = 2 * qb + 2;           // chunks of 64 keys
  const int wrow0 = q0 + wave * 16;    // this wave's first q row

  for (int c = 0; c < nc; ++c) {
    if (c + 1 < nc) STAGE(cur ^ 1);    // prefetch lands during compute
    const int k0 = c * 64;
    const bool active = (k0 <= wrow0 + 15);  // wave-uniform

    if (active) {
      const char* Kb = (const char*)Kl[cur];
      const char* Vb = (const char*)Vl[cur];

      // S^T = K Q^T : lane (lr,hi) gets keys 16t+4hi+r of q-row lr
      f32x4 st[4];
#pragma unroll
      for (int t = 0; t < 4; t++) {
        st[t] = fz;
#pragma unroll
        for (int dc = 0; dc < 4; dc++) {
          const bf16x8 kf = *(const bf16x8*)(Kb + (t * 16 + lr) * 256 +
                                             (((dc * 4 + hi) ^ lr) << 4));
          st[t] = mfma_bf16(kf, qf[dc], st[t]);
        }
      }

      const bool needMask = (k0 + 63 > wrow0);  // wave-uniform
      const int rel = wrow0 + lr - k0;
      float s2[4][4];
      float mx = -1e30f;
#pragma unroll
      for (int t = 0; t < 4; t++)
#pragma unroll
        for (int r = 0; r < 4; r++) {
          float v = st[t][r] * SC2;  // log2 domain
          if (needMask && (16 * t + 4 * hi + r > rel)) v = -1e30f;
          s2[t][r] = v;
          mx = fmaxf(mx, v);
        }
      mx = fmaxf(mx, __shfl_xor(mx, 16, 64));
      mx = fmaxf(mx, __shfl_xor(mx, 32, 64));

      // defer-max (T13): O-rescale only when running max grows by > 8 (log2)
      if (__any(mx > m_ + 8.f)) {
        float mn = fmaxf(m_, mx);
        float al = exp2f(m_ - mn);
        l_ *= al;
        m_ = mn;
        float alr[4];
#pragma unroll
        for (int r = 0; r < 4; r++) alr[r] = __shfl(al, hi * 4 + r, 64);
#pragma unroll
        for (int dt = 0; dt < 8; dt++)
#pragma unroll
          for (int r = 0; r < 4; r++) oacc[dt][r] *= alr[r];
      }

      float rs = 0.f;
#pragma unroll
      for (int t = 0; t < 4; t++) {
        float p0 = exp2f(s2[t][0] - m_), p1 = exp2f(s2[t][1] - m_);
        float p2 = exp2f(s2[t][2] - m_), p3 = exp2f(s2[t][3] - m_);
        rs += (p0 + p1) + (p2 + p3);
        bf16x4 pv = {(__bf16)p0, (__bf16)p1, (__bf16)p2, (__bf16)p3};
        *(bf16x4*)(pw + lr * 128 + (((2 * t + (hi >> 1)) ^ (lr & 7)) << 4) +
                   (hi & 1) * 8) = pv;
      }
      rs += __shfl_xor(rs, 16, 64);
      rs += __shfl_xor(rs, 32, 64);
      l_ += rs;

      // PV: pf = P[q=lr][keys 32kf+8hi..], vf = Vt[d=dt*16+lr][keys ...]
      bf16x8 pf[2];
#pragma unroll
      for (int kf_ = 0; kf_ < 2; kf_++)
        pf[kf_] = *(const bf16x8*)(pw + lr * 128 + (((4 * kf_ + hi) ^ (lr & 7)) << 4));
#pragma unroll
      for (int dt = 0; dt < 8; dt++) {
#pragma unroll
        for (int kf_ = 0; kf_ < 2; kf_++) {
          const bf16x8 vf = *(const bf16x8*)(Vb + (dt * 16 + lr) * 128 +
                                             (((kf_ * 4 + hi) ^ (lr & 7)) << 4));
          oacc[dt] = mfma_bf16(pf[kf_], vf, oacc[dt]);
        }
      }
    }

    __syncthreads();  // drains prefetch vmcnt AFTER compute; guards buffer swap
    cur ^= 1;
  }

  float rl[4];
#pragma unroll
  for (int r = 0; r < 4; r++) rl[r] = __shfl(l_, hi * 4 + r, 64);
#pragma unroll
  for (int dt = 0; dt < 8; dt++) {
#pragma unroll
    for (int r = 0; r < 4; r++) {
      int row = q0 + wave * 16 + hi * 4 + r;
      Oa[((size_t)(b * Ss) + row) * QSZ + h * HD + dt * 16 + lr] =
          (__bf16)(oacc[dt][r] / rl[r]);
    }
  }
}

extern "C" void kernel_launch(void* const* d_in, const int* in_sizes, int n_in,
                              void* d_out, int out_size, void* d_ws, size_t ws_size,
                              hipStream_t stream) {
  const int* positions = (const int*)d_in[0];
  const float* hidden = (const float*)d_in[1];
  const float* w_qkv = (const float*)d_in[2];
  const float* b_qkv = (const float*)d_in[3];
  const float* w_o = (const float*)d_in[4];
  float* out = (float*)d_out;

  char* ws = (char*)d_ws;
  __bf16* hs = (__bf16*)(ws);
  __bf16* wqkvT = (__bf16*)(ws + 33554432);
  __bf16* woT = (__bf16*)(ws + 83886080);
  __bf16* qkv = (__bf16*)(ws + 117440512);
  __bf16* q = (__bf16*)(ws + 167772160);
  __bf16* k = (__bf16*)(ws + 201326592);
  __bf16* vt = (__bf16*)(ws + 209715200);
  __bf16* attn = hs;  // hs dead after gemm1; reuse for attention output

  f2b<<<2048, 256, 0, stream>>>(hidden, hs, (long)MTOT * HIDDEN / 4);
  transpose_conv<<<(HIDDEN / 64) * (QKV_N / 64), 256, 0, stream>>>(w_qkv, wqkvT, HIDDEN, QKV_N);
  transpose_conv<<<(QSZ / 64) * (HIDDEN / 64), 256, 0, stream>>>(w_o, woT, QSZ, HIDDEN);
  // QKV: tile 128x384, grid 32*16=512 = 2 balanced passes on 256 CUs
  gemm_t<4, 6><<<(MTOT / 128) * (QKV_N / 384), 512, 131072, stream>>>(
      hs, wqkvT, b_qkv, qkv, MTOT, QKV_N, HIDDEN, 1);
  rope_qk<<<Bb * Ss, 256, 0, stream>>>(qkv, positions, q, k);
  vtrans<<<Bb * NKV * (Ss / 64), 256, 0, stream>>>(qkv, vt);
  attn_fwd<<<Bb * NH * (Ss / 128), 512, 0, stream>>>(q, k, vt, attn);
  // O-proj: tile 256x256, grid 16*16=256 = 1 balanced pass
  gemm_t<8, 4><<<(MTOT / 256) * (QSZ / 256), 512, 131072, stream>>>(
      attn, woT, nullptr, out, MTOT, QSZ, QSZ, 0);
}